// Round 13
// baseline (7687.484 us; speedup 1.0000x reference)
//
#include <hip/hip_runtime.h>
#include <cstdint>
#include <cstddef>

// ---------------- config ----------------
#define BB 16
#define SS 512
#define DD 768
#define HH 12
#define FF 3072
#define LL 12
#define DHD 64
#define MM (BB*SS)   // 8192 rows

typedef __attribute__((ext_vector_type(8))) short bf16x8;
typedef __attribute__((ext_vector_type(4))) float f32x4;

__device__ __forceinline__ ushort f2bf(float f) {
  union { float f; uint32_t u; } x; x.f = f;
  uint32_t r = x.u + 0x7FFFu + ((x.u >> 16) & 1u);
  return (ushort)(r >> 16);
}
__device__ __forceinline__ float bf2f(ushort u) {
  union { uint32_t u; float f; } x; x.u = (uint32_t)u << 16;
  return x.f;
}

__device__ __forceinline__ void glds16(const ushort* g, ushort* l) {
  __builtin_amdgcn_global_load_lds((__attribute__((address_space(1))) void*)g,
                                   (__attribute__((address_space(3))) void*)l,
                                   16, 0, 0);
}

__device__ __forceinline__ float gelu_t(float v) {
  // v * sigmoid(2y), y = 0.79788456(v + 0.044715 v^3); == tanh-gelu
  const float v2 = v * v;
  const float u = v * (-1.5957691216f - 0.0713548163f * v2);   // -2y
  return v / (1.f + __expf(u));
}

// ================= weight f32 -> bf16 conversion (6 tensors, one dispatch) ==========
__global__ __launch_bounds__(256)
void convw6(const float* __restrict__ s0, const float* __restrict__ s1,
            const float* __restrict__ s2, const float* __restrict__ s3,
            const float* __restrict__ s4, const float* __restrict__ s5,
            ushort* __restrict__ dA, ushort* __restrict__ dB, int perD, int perF)
{
  const int y = blockIdx.y;
  const int per = (y < 4) ? perD : perF;
  const int i = (blockIdx.x * 256 + threadIdx.x) * 4;
  if (i >= per) return;
  const float* s = y == 0 ? s0 : y == 1 ? s1 : y == 2 ? s2 : y == 3 ? s3 : y == 4 ? s4 : s5;
  ushort* dst = (y < 4) ? (dA + (size_t)y * perD) : (dB + (size_t)(y - 4) * perF);
  const float4 v = *(const float4*)(s + i);
  ushort4 o;
  o.x = f2bf(v.x); o.y = f2bf(v.y); o.z = f2bf(v.z); o.w = f2bf(v.w);
  *(ushort4*)(dst + i) = o;
}

// ================= embedding + LayerNorm =================
__global__ __launch_bounds__(256)
void embed_ln_kernel(const int* __restrict__ ids, const float* __restrict__ wemb,
                     const float* __restrict__ pemb, const float* __restrict__ g,
                     const float* __restrict__ bt, float* __restrict__ hf,
                     ushort* __restrict__ hb)
{
  const int row = blockIdx.x;
  const int s = row & (SS - 1);
  const int id = ids[row];
  const float* wp = wemb + (size_t)id * DD;
  const float* pp = pemb + (size_t)s * DD;
  const int tid = threadIdx.x;
  float v[3]; float sum = 0.f, sq = 0.f;
#pragma unroll
  for (int j = 0; j < 3; ++j) {
    int e = tid + j * 256;
    v[j] = wp[e] + pp[e];
    sum += v[j]; sq += v[j] * v[j];
  }
  __shared__ float red[2][4];
#pragma unroll
  for (int off = 32; off >= 1; off >>= 1) { sum += __shfl_xor(sum, off); sq += __shfl_xor(sq, off); }
  const int lane = tid & 63, wid = tid >> 6;
  if (lane == 0) { red[0][wid] = sum; red[1][wid] = sq; }
  __syncthreads();
  sum = red[0][0] + red[0][1] + red[0][2] + red[0][3];
  sq  = red[1][0] + red[1][1] + red[1][2] + red[1][3];
  const float mean = sum * (1.f / DD);
  const float var  = sq  * (1.f / DD) - mean * mean;
  const float rstd = rsqrtf(var + 1e-12f);
  const size_t base = (size_t)row * DD;
#pragma unroll
  for (int j = 0; j < 3; ++j) {
    int e = tid + j * 256;
    float o = (v[j] - mean) * rstd * g[e] + bt[e];
    hf[base + e] = o;
    hb[base + e] = f2bf(o);
  }
}

// ================= residual + two bf16 split-K partials + LayerNorm =================
__global__ __launch_bounds__(256)
void add_ln2_kernel(const float* __restrict__ res, const ushort* __restrict__ p0,
                    const ushort* __restrict__ p1, const float* __restrict__ g,
                    const float* __restrict__ bt, float* __restrict__ hf,
                    ushort* __restrict__ hb)
{
  const int row = blockIdx.x;
  const int tid = threadIdx.x;
  const size_t base = (size_t)row * DD;
  float v[3]; float sum = 0.f, sq = 0.f;
#pragma unroll
  for (int j = 0; j < 3; ++j) {
    int e = tid + j * 256;
    v[j] = res[base + e] + bf2f(p0[base + e]) + bf2f(p1[base + e]);
    sum += v[j]; sq += v[j] * v[j];
  }
  __shared__ float red[2][4];
#pragma unroll
  for (int off = 32; off >= 1; off >>= 1) { sum += __shfl_xor(sum, off); sq += __shfl_xor(sq, off); }
  const int lane = tid & 63, wid = tid >> 6;
  if (lane == 0) { red[0][wid] = sum; red[1][wid] = sq; }
  __syncthreads();
  sum = red[0][0] + red[0][1] + red[0][2] + red[0][3];
  sq  = red[1][0] + red[1][1] + red[1][2] + red[1][3];
  const float mean = sum * (1.f / DD);
  const float var  = sq  * (1.f / DD) - mean * mean;
  const float rstd = rsqrtf(var + 1e-12f);
#pragma unroll
  for (int j = 0; j < 3; ++j) {
    int e = tid + j * 256;
    float o = (v[j] - mean) * rstd * g[e] + bt[e];
    hf[base + e] = o;
    hb[base + e] = f2bf(o);
  }
}

// ================= GEMM: C[M,N] = A[M,K](bf16) @ Bw[N,K](bf16)^T + bias =================
// m97 schedule: 128x128 tile, BK=32, double-buffered (32KB -> 5 blocks/CU = 160KB),
// XOR-swizzled staging (0 bank conflicts), swapped-operand MFMA, vectorized epilogue.
// EPI 0: bf16 out; 2: bf16 out + gelu. TRV: sub==2 writes vT[b][h][d][s].
template<int EPI, bool TRV>
__global__ __launch_bounds__(256, 5)
void gemm_ker(const ushort* __restrict__ A,
              const ushort* __restrict__ B0, const ushort* __restrict__ B1,
              const ushort* __restrict__ B2,
              const float* __restrict__ bias0, const float* __restrict__ bias1,
              const float* __restrict__ bias2,
              void* __restrict__ C0, void* __restrict__ C1, void* __restrict__ C2,
              int Kdim, int nblk)
{
  __shared__ ushort As[2][128 * 32];
  __shared__ ushort Bs[2][128 * 32];

  int id = blockIdx.y * gridDim.x + blockIdx.x;
  const int chunk = (gridDim.x * gridDim.y) >> 3;
  id = (id & 7) * chunk + (id >> 3);
  const int bm = id & 63;
  const int bnAll = id >> 6;
  const int sub = bnAll / nblk;
  const int bn = bnAll - sub * nblk;

  const ushort* Bw  = sub == 0 ? B0 : (sub == 1 ? B1 : B2);
  const float* bias = sub == 0 ? bias0 : (sub == 1 ? bias1 : bias2);
  const int Ndim = nblk * 128;

  const int tid = threadIdx.x;
  const int l = tid & 63, w = tid >> 6;
  const int wm = w >> 1, wn = w & 1;
  const int fr = l & 15, fg = l >> 4;

  const int srow_in = l >> 2;
  const int gks = ((l & 3) ^ ((l >> 3) & 3)) * 8;
  const ushort* Agl0 = A  + (size_t)(bm * 128 + w * 16 + srow_in) * Kdim + gks;
  const ushort* Agl1 = Agl0 + (size_t)64 * Kdim;
  const ushort* Bgl0 = Bw + (size_t)(bn * 128 + w * 16 + srow_in) * Kdim + gks;
  const ushort* Bgl1 = Bgl0 + (size_t)64 * Kdim;

  auto stage = [&](int b, int kt) {
    const int ko = kt * 32;
    ushort* al = &As[b][w * 64 * 8];
    ushort* bl = &Bs[b][w * 64 * 8];
    glds16(Agl0 + ko, al);
    glds16(Agl1 + ko, al + 256 * 8);
    glds16(Bgl0 + ko, bl);
    glds16(Bgl1 + ko, bl + 256 * 8);
  };

  const int se = (fg ^ ((fr >> 1) & 3)) * 8;

  f32x4 acc[4][4];
#pragma unroll
  for (int i = 0; i < 4; ++i)
#pragma unroll
    for (int j = 0; j < 4; ++j) acc[i][j] = f32x4{0.f, 0.f, 0.f, 0.f};

  stage(0, 0);
  __syncthreads();

  const int nk = Kdim >> 5;
  int cur = 0;
  for (int kt = 0; kt < nk; ++kt) {
    if (kt + 1 < nk) stage(cur ^ 1, kt + 1);

    bf16x8 af[4], bfv[4];
#pragma unroll
    for (int i = 0; i < 4; ++i)
      af[i]  = *(const bf16x8*)&As[cur][(wm * 64 + i * 16 + fr) * 32 + se];
#pragma unroll
    for (int j = 0; j < 4; ++j)
      bfv[j] = *(const bf16x8*)&Bs[cur][(wn * 64 + j * 16 + fr) * 32 + se];

    __builtin_amdgcn_s_setprio(1);
#pragma unroll
    for (int i = 0; i < 4; ++i)
#pragma unroll
      for (int j = 0; j < 4; ++j)
        acc[i][j] = __builtin_amdgcn_mfma_f32_16x16x32_bf16(bfv[j], af[i], acc[i][j], 0, 0, 0);
    __builtin_amdgcn_s_setprio(0);

    __syncthreads();
    cur ^= 1;
  }

#pragma unroll
  for (int i = 0; i < 4; ++i) {
    const int row_g = bm * 128 + wm * 64 + i * 16 + fr;
#pragma unroll
    for (int j = 0; j < 4; ++j) {
      const int col = bn * 128 + wn * 64 + j * 16 + fg * 4;
      const float4 bv4 = *(const float4*)&bias[col];
      const float v0 = acc[i][j][0] + bv4.x;
      const float v1 = acc[i][j][1] + bv4.y;
      const float v2 = acc[i][j][2] + bv4.z;
      const float v3 = acc[i][j][3] + bv4.w;
      if (TRV && sub == 2) {
        const int b_ = row_g >> 9, s_ = row_g & 511;
        const int h_ = col >> 6, d0 = col & 63;
        ushort* vp = (ushort*)C2 + (((size_t)(b_ * HH + h_) * DHD + d0) * SS + s_);
        vp[0] = f2bf(v0); vp[SS] = f2bf(v1); vp[2 * SS] = f2bf(v2); vp[3 * SS] = f2bf(v3);
      } else if (EPI == 2) {
        ushort4 o4;
        o4.x = f2bf(gelu_t(v0)); o4.y = f2bf(gelu_t(v1));
        o4.z = f2bf(gelu_t(v2)); o4.w = f2bf(gelu_t(v3));
        *(ushort4*)&((ushort*)C0)[(size_t)row_g * Ndim + col] = o4;
      } else {
        void* Cout = sub == 0 ? C0 : (sub == 1 ? C1 : C2);
        ushort4 o4;
        o4.x = f2bf(v0); o4.y = f2bf(v1); o4.z = f2bf(v2); o4.w = f2bf(v3);
        *(ushort4*)&((ushort*)Cout)[(size_t)row_g * Ndim + col] = o4;
      }
    }
  }
}

// ================= split-K=2 GEMM for N=768 (O-proj, Wd) — bf16 partials =================
// grid (64, 12): y encodes bn (6) x sk (2). bf16 partials to P0/P1; bias in sk==0.
__global__ __launch_bounds__(256, 5)
void gemm_sk(const ushort* __restrict__ A, const ushort* __restrict__ Bw,
             const float* __restrict__ bias, ushort* __restrict__ P0,
             ushort* __restrict__ P1, int Kdim)
{
  __shared__ ushort As[2][128 * 32];
  __shared__ ushort Bs[2][128 * 32];

  int id = blockIdx.y * gridDim.x + blockIdx.x;
  const int chunk = (gridDim.x * gridDim.y) >> 3;
  id = (id & 7) * chunk + (id >> 3);
  const int bm = id & 63;
  const int rest = id >> 6;
  const int bn = rest >> 1;
  const int sk = rest & 1;

  const int Kh = Kdim >> 1;

  const int tid = threadIdx.x;
  const int l = tid & 63, w = tid >> 6;
  const int wm = w >> 1, wn = w & 1;
  const int fr = l & 15, fg = l >> 4;

  const int srow_in = l >> 2;
  const int gks = ((l & 3) ^ ((l >> 3) & 3)) * 8;
  const ushort* Agl0 = A  + (size_t)(bm * 128 + w * 16 + srow_in) * Kdim + sk * Kh + gks;
  const ushort* Agl1 = Agl0 + (size_t)64 * Kdim;
  const ushort* Bgl0 = Bw + (size_t)(bn * 128 + w * 16 + srow_in) * Kdim + sk * Kh + gks;
  const ushort* Bgl1 = Bgl0 + (size_t)64 * Kdim;

  auto stage = [&](int b, int kt) {
    const int ko = kt * 32;
    ushort* al = &As[b][w * 64 * 8];
    ushort* bl = &Bs[b][w * 64 * 8];
    glds16(Agl0 + ko, al);
    glds16(Agl1 + ko, al + 256 * 8);
    glds16(Bgl0 + ko, bl);
    glds16(Bgl1 + ko, bl + 256 * 8);
  };

  const int se = (fg ^ ((fr >> 1) & 3)) * 8;

  f32x4 acc[4][4];
#pragma unroll
  for (int i = 0; i < 4; ++i)
#pragma unroll
    for (int j = 0; j < 4; ++j) acc[i][j] = f32x4{0.f, 0.f, 0.f, 0.f};

  stage(0, 0);
  __syncthreads();

  const int nk = Kh >> 5;
  int cur = 0;
  for (int kt = 0; kt < nk; ++kt) {
    if (kt + 1 < nk) stage(cur ^ 1, kt + 1);

    bf16x8 af[4], bfv[4];
#pragma unroll
    for (int i = 0; i < 4; ++i)
      af[i]  = *(const bf16x8*)&As[cur][(wm * 64 + i * 16 + fr) * 32 + se];
#pragma unroll
    for (int j = 0; j < 4; ++j)
      bfv[j] = *(const bf16x8*)&Bs[cur][(wn * 64 + j * 16 + fr) * 32 + se];

    __builtin_amdgcn_s_setprio(1);
#pragma unroll
    for (int i = 0; i < 4; ++i)
#pragma unroll
      for (int j = 0; j < 4; ++j)
        acc[i][j] = __builtin_amdgcn_mfma_f32_16x16x32_bf16(bfv[j], af[i], acc[i][j], 0, 0, 0);
    __builtin_amdgcn_s_setprio(0);

    __syncthreads();
    cur ^= 1;
  }

  ushort* P = sk ? P1 : P0;
  const float bs = sk ? 0.f : 1.f;
#pragma unroll
  for (int i = 0; i < 4; ++i) {
    const int row_g = bm * 128 + wm * 64 + i * 16 + fr;
#pragma unroll
    for (int j = 0; j < 4; ++j) {
      const int col = bn * 128 + wn * 64 + j * 16 + fg * 4;
      const float4 bv4 = *(const float4*)&bias[col];
      ushort4 o4;
      o4.x = f2bf(acc[i][j][0] + bv4.x * bs);
      o4.y = f2bf(acc[i][j][1] + bv4.y * bs);
      o4.z = f2bf(acc[i][j][2] + bv4.z * bs);
      o4.w = f2bf(acc[i][j][3] + bv4.w * bs);
      *(ushort4*)&P[(size_t)row_g * DD + col] = o4;
    }
  }
}

// ================= fused flash attention (V pre-transposed, QBLK=128) =================
// 512 threads = 8 waves, each wave owns 16 q-rows. grid (S/128, B*H).
__global__ __launch_bounds__(512, 2)
void attn_kernel(const ushort* __restrict__ qb, const ushort* __restrict__ kb,
                 const ushort* __restrict__ vt, const float* __restrict__ relt,
                 const float* __restrict__ amask, ushort* __restrict__ ctxb)
{
  __shared__ ushort Kt[128][72];
  __shared__ ushort Vt[64][136];
  __shared__ ushort Pl[128][136];
  __shared__ float am_lds[512];
  __shared__ float rel_lds[1024];

  const int tid = threadIdx.x, lane = tid & 63, w = tid >> 6;

  int lin = blockIdx.y * gridDim.x + blockIdx.x;        // 0..767
  lin = (lin & 7) * 96 + (lin >> 3);
  const int qt = lin & 3;
  const int bh = lin >> 2;
  const int b = bh / HH, h = bh - b * HH;
  const int fr = lane & 15, fg = lane >> 4;

  am_lds[tid] = (1.0f - amask[b * SS + tid]) * -10000.0f;
  {
    int d0 = tid - 512;
    d0 = max(-128, d0);
    rel_lds[tid] = relt[(d0 + 128) * HH + h];
    int d1 = tid;
    d1 = min(128, d1);
    rel_lds[tid + 512] = relt[(d1 + 128) * HH + h];
  }

  bf16x8 qf[2];
  {
    const int qrow = qt * 128 + w * 16 + fr;
    const ushort* p = qb + ((size_t)(b * SS + qrow) * DD) + h * DHD + fg * 8;
    qf[0] = *(const bf16x8*)p;
    qf[1] = *(const bf16x8*)(p + 32);
  }

  f32x4 o[4];
  float mrow[4], lrow[4];
#pragma unroll
  for (int r = 0; r < 4; ++r) { mrow[r] = -1e30f; lrow[r] = 0.f; }
#pragma unroll
  for (int d = 0; d < 4; ++d) o[d] = f32x4{0.f, 0.f, 0.f, 0.f};

  const int skr = tid >> 2;
  const int shd = (tid & 3) * 16;
  const int vrow = tid >> 3;
  const int vcg  = (tid & 7) * 16;
  const ushort* vgl = vt + ((size_t)bh * DHD + vrow) * SS + vcg;

  const int qg0 = qt * 128 + w * 16;

  for (int kt = 0; kt < 4; ++kt) {
    const size_t gbase = ((size_t)(b * SS + kt * 128 + skr) * DD) + h * DHD + shd;
    int4 kr0 = *(const int4*)(kb + gbase);
    int4 kr1 = *(const int4*)(kb + gbase + 8);
    const ushort* vp = vgl + kt * 128;
    int4 vr0 = *(const int4*)(vp);
    int4 vr1 = *(const int4*)(vp + 8);

    __syncthreads();
    *(int4*)&Kt[skr][shd]     = kr0;
    *(int4*)&Kt[skr][shd + 8] = kr1;
    *(int4*)&Vt[vrow][vcg]     = vr0;
    *(int4*)&Vt[vrow][vcg + 8] = vr1;
    __syncthreads();

    float sv[8][4];
    __builtin_amdgcn_s_setprio(1);
#pragma unroll
    for (int kc = 0; kc < 8; ++kc) {
      f32x4 s = f32x4{0.f, 0.f, 0.f, 0.f};
      bf16x8 kf0 = *(const bf16x8*)&Kt[kc * 16 + fr][fg * 8];
      bf16x8 kf1 = *(const bf16x8*)&Kt[kc * 16 + fr][32 + fg * 8];
      s = __builtin_amdgcn_mfma_f32_16x16x32_bf16(qf[0], kf0, s, 0, 0, 0);
      s = __builtin_amdgcn_mfma_f32_16x16x32_bf16(qf[1], kf1, s, 0, 0, 0);
      const int col = kt * 128 + kc * 16 + fr;
      const float am = am_lds[col];
      const int ridx = col - qg0 - fg * 4 + 512;
#pragma unroll
      for (int r = 0; r < 4; ++r)
        sv[kc][r] = s[r] * 0.125f + rel_lds[ridx - r] + am;
    }
    __builtin_amdgcn_s_setprio(0);

    float ef[4];
#pragma unroll
    for (int r = 0; r < 4; ++r) {
      float tmax = sv[0][r];
#pragma unroll
      for (int kc = 1; kc < 8; ++kc) tmax = fmaxf(tmax, sv[kc][r]);
#pragma unroll
      for (int off = 1; off < 16; off <<= 1) tmax = fmaxf(tmax, __shfl_xor(tmax, off));
      const float mnew = fmaxf(mrow[r], tmax);
      ef[r] = __expf(mrow[r] - mnew);
      float psum = 0.f;
      const int prow = w * 16 + fg * 4 + r;
#pragma unroll
      for (int kc = 0; kc < 8; ++kc) {
        float p = __expf(sv[kc][r] - mnew);
        psum += p;
        Pl[prow][kc * 16 + fr] = f2bf(p);
      }
#pragma unroll
      for (int off = 1; off < 16; off <<= 1) psum += __shfl_xor(psum, off);
      lrow[r] = lrow[r] * ef[r] + psum;
      mrow[r] = mnew;
    }
#pragma unroll
    for (int dc = 0; dc < 4; ++dc)
#pragma unroll
      for (int r = 0; r < 4; ++r) o[dc][r] *= ef[r];
    __syncthreads();

    __builtin_amdgcn_s_setprio(1);
#pragma unroll
    for (int dc = 0; dc < 4; ++dc)
#pragma unroll
      for (int ks = 0; ks < 4; ++ks) {
        bf16x8 pf = *(const bf16x8*)&Pl[w * 16 + fr][ks * 32 + fg * 8];
        bf16x8 vf = *(const bf16x8*)&Vt[dc * 16 + fr][ks * 32 + fg * 8];
        o[dc] = __builtin_amdgcn_mfma_f32_16x16x32_bf16(pf, vf, o[dc], 0, 0, 0);
      }
    __builtin_amdgcn_s_setprio(0);
  }

#pragma unroll
  for (int dc = 0; dc < 4; ++dc)
#pragma unroll
    for (int r = 0; r < 4; ++r) {
      const int qg = qt * 128 + w * 16 + fg * 4 + r;
      const float v = o[dc][r] / lrow[r];
      ctxb[((size_t)(b * SS + qg) * DD) + h * DHD + dc * 16 + fr] = f2bf(v);
    }
}

// ================= host launch =================
extern "C" void kernel_launch(void* const* d_in, const int* in_sizes, int n_in,
                              void* d_out, int out_size, void* d_ws, size_t ws_size,
                              hipStream_t stream) {
  const int*   ids   = (const int*)d_in[0];
  const float* amask = (const float*)d_in[1];
  const float* wemb  = (const float*)d_in[2];
  const float* pemb  = (const float*)d_in[3];
  const float* eln_w = (const float*)d_in[4];
  const float* eln_b = (const float*)d_in[5];
  const float* relt  = (const float*)d_in[6];
  const float* Wq    = (const float*)d_in[7];
  const float* bq    = (const float*)d_in[8];
  const float* Wk    = (const float*)d_in[9];
  const float* bk    = (const float*)d_in[10];
  const float* Wv    = (const float*)d_in[11];
  const float* bv    = (const float*)d_in[12];
  const float* Wo    = (const float*)d_in[13];
  const float* bo    = (const float*)d_in[14];
  const float* aln_w = (const float*)d_in[15];
  const float* aln_b = (const float*)d_in[16];
  const float* Wi    = (const float*)d_in[17];
  const float* bi    = (const float*)d_in[18];
  const float* Wd    = (const float*)d_in[19];
  const float* bd    = (const float*)d_in[20];
  const float* oln_w = (const float*)d_in[21];
  const float* oln_b = (const float*)d_in[22];

  size_t off = 0;
  auto carve = [&](size_t bytes) -> void* {
    void* r = (char*)d_ws + off;
    off += (bytes + 255) & ~(size_t)255;
    return r;
  };
  float*  hf     = (float*) carve((size_t)MM * DD * 4);
  ushort* hb     = (ushort*)carve((size_t)MM * DD * 2);
  ushort* qbuf   = (ushort*)carve((size_t)MM * DD * 2);
  ushort* kbuf   = (ushort*)carve((size_t)MM * DD * 2);
  ushort* vbuf   = (ushort*)carve((size_t)MM * DD * 2);   // vT[b][h][d][s]
  ushort* ctxb   = (ushort*)carve((size_t)MM * DD * 2);
  ushort* gout   = (ushort*)carve((size_t)MM * DD * 2);   // split-K partial 0 (bf16)
  ushort* gout2  = (ushort*)carve((size_t)MM * DD * 2);   // split-K partial 1 (bf16)
  ushort* interb = (ushort*)carve((size_t)MM * FF * 2);
  const int PD = DD * DD;
  const int PF = FF * DD;
  ushort* wBded  = (ushort*)carve((size_t)2 * PF * 2);    // Wi,Wd bf16 (dedicated)

  ushort* wA = interb;   // Wq,Wk,Wv,Wo bf16 in interb's dead window

  embed_ln_kernel<<<MM, 256, 0, stream>>>(ids, wemb, pemb, eln_w, eln_b, hf, hb);

  const dim3 gQKV(MM / 128, 3 * (DD / 128));  // 64 x 18
  const dim3 gSK(MM / 128, 2 * (DD / 128));   // 64 x 12 (split-K=2)
  const dim3 gF(MM / 128, FF / 128);          // 64 x 24
  const dim3 gA(SS / 128, BB * HH);           // 4 x 192
  const dim3 gC(PF / 1024, 6);                // 2304 x 6

  for (int l = 0; l < LL; ++l) {
    const size_t wo  = (size_t)l * PD;
    const size_t wio = (size_t)l * PF;

    convw6<<<gC, 256, 0, stream>>>(Wq + wo, Wk + wo, Wv + wo, Wo + wo,
                                   Wi + wio, Wd + wio, wA, wBded, PD, PF);

    gemm_ker<0, true><<<gQKV, 256, 0, stream>>>(hb, wA, wA + PD, wA + 2 * PD,
                                                bq + l * DD, bk + l * DD, bv + l * DD,
                                                qbuf, kbuf, vbuf, DD, DD / 128);

    attn_kernel<<<gA, 512, 0, stream>>>(qbuf, kbuf, vbuf, relt, amask, ctxb);

    gemm_sk<<<gSK, 256, 0, stream>>>(ctxb, wA + 3 * PD, bo + l * DD, gout, gout2, DD);
    add_ln2_kernel<<<MM, 256, 0, stream>>>(hf, gout, gout2,
                                           aln_w + l * DD, aln_b + l * DD, hf, hb);

    gemm_ker<2, false><<<gF, 256, 0, stream>>>(hb, wBded, wBded, wBded,
                                               bi + l * FF, bi + l * FF, bi + l * FF,
                                               interb, interb, interb, DD, FF / 128);
    gemm_sk<<<gSK, 256, 0, stream>>>(interb, wBded + PF, bd + l * DD, gout, gout2, FF);

    float* outp = (l == LL - 1) ? (float*)d_out : hf;
    add_ln2_kernel<<<MM, 256, 0, stream>>>(hf, gout, gout2,
                                           oln_w + l * DD, oln_b + l * DD, outp, hb);
  }
}

// Round 14
// 3347.538 us; speedup vs baseline: 2.2965x; 2.2965x over previous
//
#include <hip/hip_runtime.h>
#include <cstdint>
#include <cstddef>

// ---------------- config ----------------
#define BB 16
#define SS 512
#define DD 768
#define HH 12
#define FF 3072
#define LL 12
#define DHD 64
#define MM (BB*SS)   // 8192 rows

typedef __attribute__((ext_vector_type(8))) short bf16x8;
typedef __attribute__((ext_vector_type(4))) float f32x4;

__device__ __forceinline__ ushort f2bf(float f) {
  union { float f; uint32_t u; } x; x.f = f;
  uint32_t r = x.u + 0x7FFFu + ((x.u >> 16) & 1u);
  return (ushort)(r >> 16);
}
__device__ __forceinline__ float bf2f(ushort u) {
  union { uint32_t u; float f; } x; x.u = (uint32_t)u << 16;
  return x.f;
}

__device__ __forceinline__ void glds16(const ushort* g, ushort* l) {
  __builtin_amdgcn_global_load_lds((__attribute__((address_space(1))) void*)g,
                                   (__attribute__((address_space(3))) void*)l,
                                   16, 0, 0);
}

__device__ __forceinline__ float gelu_t(float v) {
  // v * sigmoid(2y), y = 0.79788456(v + 0.044715 v^3); == tanh-gelu
  const float v2 = v * v;
  const float u = v * (-1.5957691216f - 0.0713548163f * v2);   // -2y
  return v / (1.f + __expf(u));
}

// ================= weight f32 -> bf16 conversion (6 tensors, one dispatch) ==========
__global__ __launch_bounds__(256)
void convw6(const float* __restrict__ s0, const float* __restrict__ s1,
            const float* __restrict__ s2, const float* __restrict__ s3,
            const float* __restrict__ s4, const float* __restrict__ s5,
            ushort* __restrict__ dA, ushort* __restrict__ dB, int perD, int perF)
{
  const int y = blockIdx.y;
  const int per = (y < 4) ? perD : perF;
  const int i = (blockIdx.x * 256 + threadIdx.x) * 4;
  if (i >= per) return;
  const float* s = y == 0 ? s0 : y == 1 ? s1 : y == 2 ? s2 : y == 3 ? s3 : y == 4 ? s4 : s5;
  ushort* dst = (y < 4) ? (dA + (size_t)y * perD) : (dB + (size_t)(y - 4) * perF);
  const float4 v = *(const float4*)(s + i);
  ushort4 o;
  o.x = f2bf(v.x); o.y = f2bf(v.y); o.z = f2bf(v.z); o.w = f2bf(v.w);
  *(ushort4*)(dst + i) = o;
}

// ================= embedding + LayerNorm =================
__global__ __launch_bounds__(256)
void embed_ln_kernel(const int* __restrict__ ids, const float* __restrict__ wemb,
                     const float* __restrict__ pemb, const float* __restrict__ g,
                     const float* __restrict__ bt, float* __restrict__ hf,
                     ushort* __restrict__ hb)
{
  const int row = blockIdx.x;
  const int s = row & (SS - 1);
  const int id = ids[row];
  const float* wp = wemb + (size_t)id * DD;
  const float* pp = pemb + (size_t)s * DD;
  const int tid = threadIdx.x;
  float v[3]; float sum = 0.f, sq = 0.f;
#pragma unroll
  for (int j = 0; j < 3; ++j) {
    int e = tid + j * 256;
    v[j] = wp[e] + pp[e];
    sum += v[j]; sq += v[j] * v[j];
  }
  __shared__ float red[2][4];
#pragma unroll
  for (int off = 32; off >= 1; off >>= 1) { sum += __shfl_xor(sum, off); sq += __shfl_xor(sq, off); }
  const int lane = tid & 63, wid = tid >> 6;
  if (lane == 0) { red[0][wid] = sum; red[1][wid] = sq; }
  __syncthreads();
  sum = red[0][0] + red[0][1] + red[0][2] + red[0][3];
  sq  = red[1][0] + red[1][1] + red[1][2] + red[1][3];
  const float mean = sum * (1.f / DD);
  const float var  = sq  * (1.f / DD) - mean * mean;
  const float rstd = rsqrtf(var + 1e-12f);
  const size_t base = (size_t)row * DD;
#pragma unroll
  for (int j = 0; j < 3; ++j) {
    int e = tid + j * 256;
    float o = (v[j] - mean) * rstd * g[e] + bt[e];
    hf[base + e] = o;
    hb[base + e] = f2bf(o);
  }
}

// ================= residual + two bf16 split-K partials + LayerNorm =================
__global__ __launch_bounds__(256)
void add_ln2_kernel(const float* __restrict__ res, const ushort* __restrict__ p0,
                    const ushort* __restrict__ p1, const float* __restrict__ g,
                    const float* __restrict__ bt, float* __restrict__ hf,
                    ushort* __restrict__ hb)
{
  const int row = blockIdx.x;
  const int tid = threadIdx.x;
  const size_t base = (size_t)row * DD;
  float v[3]; float sum = 0.f, sq = 0.f;
#pragma unroll
  for (int j = 0; j < 3; ++j) {
    int e = tid + j * 256;
    v[j] = res[base + e] + bf2f(p0[base + e]) + bf2f(p1[base + e]);
    sum += v[j]; sq += v[j] * v[j];
  }
  __shared__ float red[2][4];
#pragma unroll
  for (int off = 32; off >= 1; off >>= 1) { sum += __shfl_xor(sum, off); sq += __shfl_xor(sq, off); }
  const int lane = tid & 63, wid = tid >> 6;
  if (lane == 0) { red[0][wid] = sum; red[1][wid] = sq; }
  __syncthreads();
  sum = red[0][0] + red[0][1] + red[0][2] + red[0][3];
  sq  = red[1][0] + red[1][1] + red[1][2] + red[1][3];
  const float mean = sum * (1.f / DD);
  const float var  = sq  * (1.f / DD) - mean * mean;
  const float rstd = rsqrtf(var + 1e-12f);
#pragma unroll
  for (int j = 0; j < 3; ++j) {
    int e = tid + j * 256;
    float o = (v[j] - mean) * rstd * g[e] + bt[e];
    hf[base + e] = o;
    hb[base + e] = f2bf(o);
  }
}

// ================= GEMM: C[M,N] = A[M,K](bf16) @ Bw[N,K](bf16)^T + bias =================
// m97 schedule: 128x128 tile, BK=32, double-buffered (32KB -> 4 blocks/CU),
// XOR-swizzled staging (0 bank conflicts), swapped-operand MFMA, vectorized epilogue.
// NOTE: do NOT raise the occupancy bound past 4 — at 5 the allocator drops below
// 64 VGPR, spills acc to scratch, and WRITE_SIZE explodes 49->713MB (round 13).
// EPI 0: bf16 out; 2: bf16 out + gelu. TRV: sub==2 writes vT[b][h][d][s].
template<int EPI, bool TRV>
__global__ __launch_bounds__(256, 4)
void gemm_ker(const ushort* __restrict__ A,
              const ushort* __restrict__ B0, const ushort* __restrict__ B1,
              const ushort* __restrict__ B2,
              const float* __restrict__ bias0, const float* __restrict__ bias1,
              const float* __restrict__ bias2,
              void* __restrict__ C0, void* __restrict__ C1, void* __restrict__ C2,
              int Kdim, int nblk)
{
  __shared__ ushort As[2][128 * 32];
  __shared__ ushort Bs[2][128 * 32];

  int id = blockIdx.y * gridDim.x + blockIdx.x;
  const int chunk = (gridDim.x * gridDim.y) >> 3;
  id = (id & 7) * chunk + (id >> 3);
  const int bm = id & 63;
  const int bnAll = id >> 6;
  const int sub = bnAll / nblk;
  const int bn = bnAll - sub * nblk;

  const ushort* Bw  = sub == 0 ? B0 : (sub == 1 ? B1 : B2);
  const float* bias = sub == 0 ? bias0 : (sub == 1 ? bias1 : bias2);
  const int Ndim = nblk * 128;

  const int tid = threadIdx.x;
  const int l = tid & 63, w = tid >> 6;
  const int wm = w >> 1, wn = w & 1;
  const int fr = l & 15, fg = l >> 4;

  const int srow_in = l >> 2;
  const int gks = ((l & 3) ^ ((l >> 3) & 3)) * 8;
  const ushort* Agl0 = A  + (size_t)(bm * 128 + w * 16 + srow_in) * Kdim + gks;
  const ushort* Agl1 = Agl0 + (size_t)64 * Kdim;
  const ushort* Bgl0 = Bw + (size_t)(bn * 128 + w * 16 + srow_in) * Kdim + gks;
  const ushort* Bgl1 = Bgl0 + (size_t)64 * Kdim;

  auto stage = [&](int b, int kt) {
    const int ko = kt * 32;
    ushort* al = &As[b][w * 64 * 8];
    ushort* bl = &Bs[b][w * 64 * 8];
    glds16(Agl0 + ko, al);
    glds16(Agl1 + ko, al + 256 * 8);
    glds16(Bgl0 + ko, bl);
    glds16(Bgl1 + ko, bl + 256 * 8);
  };

  const int se = (fg ^ ((fr >> 1) & 3)) * 8;

  f32x4 acc[4][4];
#pragma unroll
  for (int i = 0; i < 4; ++i)
#pragma unroll
    for (int j = 0; j < 4; ++j) acc[i][j] = f32x4{0.f, 0.f, 0.f, 0.f};

  stage(0, 0);
  __syncthreads();

  const int nk = Kdim >> 5;
  int cur = 0;
  for (int kt = 0; kt < nk; ++kt) {
    if (kt + 1 < nk) stage(cur ^ 1, kt + 1);

    bf16x8 af[4], bfv[4];
#pragma unroll
    for (int i = 0; i < 4; ++i)
      af[i]  = *(const bf16x8*)&As[cur][(wm * 64 + i * 16 + fr) * 32 + se];
#pragma unroll
    for (int j = 0; j < 4; ++j)
      bfv[j] = *(const bf16x8*)&Bs[cur][(wn * 64 + j * 16 + fr) * 32 + se];

    __builtin_amdgcn_s_setprio(1);
#pragma unroll
    for (int i = 0; i < 4; ++i)
#pragma unroll
      for (int j = 0; j < 4; ++j)
        acc[i][j] = __builtin_amdgcn_mfma_f32_16x16x32_bf16(bfv[j], af[i], acc[i][j], 0, 0, 0);
    __builtin_amdgcn_s_setprio(0);

    __syncthreads();
    cur ^= 1;
  }

#pragma unroll
  for (int i = 0; i < 4; ++i) {
    const int row_g = bm * 128 + wm * 64 + i * 16 + fr;
#pragma unroll
    for (int j = 0; j < 4; ++j) {
      const int col = bn * 128 + wn * 64 + j * 16 + fg * 4;
      const float4 bv4 = *(const float4*)&bias[col];
      const float v0 = acc[i][j][0] + bv4.x;
      const float v1 = acc[i][j][1] + bv4.y;
      const float v2 = acc[i][j][2] + bv4.z;
      const float v3 = acc[i][j][3] + bv4.w;
      if (TRV && sub == 2) {
        const int b_ = row_g >> 9, s_ = row_g & 511;
        const int h_ = col >> 6, d0 = col & 63;
        ushort* vp = (ushort*)C2 + (((size_t)(b_ * HH + h_) * DHD + d0) * SS + s_);
        vp[0] = f2bf(v0); vp[SS] = f2bf(v1); vp[2 * SS] = f2bf(v2); vp[3 * SS] = f2bf(v3);
      } else if (EPI == 2) {
        ushort4 o4;
        o4.x = f2bf(gelu_t(v0)); o4.y = f2bf(gelu_t(v1));
        o4.z = f2bf(gelu_t(v2)); o4.w = f2bf(gelu_t(v3));
        *(ushort4*)&((ushort*)C0)[(size_t)row_g * Ndim + col] = o4;
      } else {
        void* Cout = sub == 0 ? C0 : (sub == 1 ? C1 : C2);
        ushort4 o4;
        o4.x = f2bf(v0); o4.y = f2bf(v1); o4.z = f2bf(v2); o4.w = f2bf(v3);
        *(ushort4*)&((ushort*)Cout)[(size_t)row_g * Ndim + col] = o4;
      }
    }
  }
}

// ================= split-K=2 GEMM for N=768 (O-proj, Wd) — bf16 partials =================
// grid (64, 12): y encodes bn (6) x sk (2). bf16 partials to P0/P1; bias in sk==0.
__global__ __launch_bounds__(256, 4)
void gemm_sk(const ushort* __restrict__ A, const ushort* __restrict__ Bw,
             const float* __restrict__ bias, ushort* __restrict__ P0,
             ushort* __restrict__ P1, int Kdim)
{
  __shared__ ushort As[2][128 * 32];
  __shared__ ushort Bs[2][128 * 32];

  int id = blockIdx.y * gridDim.x + blockIdx.x;
  const int chunk = (gridDim.x * gridDim.y) >> 3;
  id = (id & 7) * chunk + (id >> 3);
  const int bm = id & 63;
  const int rest = id >> 6;
  const int bn = rest >> 1;
  const int sk = rest & 1;

  const int Kh = Kdim >> 1;

  const int tid = threadIdx.x;
  const int l = tid & 63, w = tid >> 6;
  const int wm = w >> 1, wn = w & 1;
  const int fr = l & 15, fg = l >> 4;

  const int srow_in = l >> 2;
  const int gks = ((l & 3) ^ ((l >> 3) & 3)) * 8;
  const ushort* Agl0 = A  + (size_t)(bm * 128 + w * 16 + srow_in) * Kdim + sk * Kh + gks;
  const ushort* Agl1 = Agl0 + (size_t)64 * Kdim;
  const ushort* Bgl0 = Bw + (size_t)(bn * 128 + w * 16 + srow_in) * Kdim + sk * Kh + gks;
  const ushort* Bgl1 = Bgl0 + (size_t)64 * Kdim;

  auto stage = [&](int b, int kt) {
    const int ko = kt * 32;
    ushort* al = &As[b][w * 64 * 8];
    ushort* bl = &Bs[b][w * 64 * 8];
    glds16(Agl0 + ko, al);
    glds16(Agl1 + ko, al + 256 * 8);
    glds16(Bgl0 + ko, bl);
    glds16(Bgl1 + ko, bl + 256 * 8);
  };

  const int se = (fg ^ ((fr >> 1) & 3)) * 8;

  f32x4 acc[4][4];
#pragma unroll
  for (int i = 0; i < 4; ++i)
#pragma unroll
    for (int j = 0; j < 4; ++j) acc[i][j] = f32x4{0.f, 0.f, 0.f, 0.f};

  stage(0, 0);
  __syncthreads();

  const int nk = Kh >> 5;
  int cur = 0;
  for (int kt = 0; kt < nk; ++kt) {
    if (kt + 1 < nk) stage(cur ^ 1, kt + 1);

    bf16x8 af[4], bfv[4];
#pragma unroll
    for (int i = 0; i < 4; ++i)
      af[i]  = *(const bf16x8*)&As[cur][(wm * 64 + i * 16 + fr) * 32 + se];
#pragma unroll
    for (int j = 0; j < 4; ++j)
      bfv[j] = *(const bf16x8*)&Bs[cur][(wn * 64 + j * 16 + fr) * 32 + se];

    __builtin_amdgcn_s_setprio(1);
#pragma unroll
    for (int i = 0; i < 4; ++i)
#pragma unroll
      for (int j = 0; j < 4; ++j)
        acc[i][j] = __builtin_amdgcn_mfma_f32_16x16x32_bf16(bfv[j], af[i], acc[i][j], 0, 0, 0);
    __builtin_amdgcn_s_setprio(0);

    __syncthreads();
    cur ^= 1;
  }

  ushort* P = sk ? P1 : P0;
  const float bs = sk ? 0.f : 1.f;
#pragma unroll
  for (int i = 0; i < 4; ++i) {
    const int row_g = bm * 128 + wm * 64 + i * 16 + fr;
#pragma unroll
    for (int j = 0; j < 4; ++j) {
      const int col = bn * 128 + wn * 64 + j * 16 + fg * 4;
      const float4 bv4 = *(const float4*)&bias[col];
      ushort4 o4;
      o4.x = f2bf(acc[i][j][0] + bv4.x * bs);
      o4.y = f2bf(acc[i][j][1] + bv4.y * bs);
      o4.z = f2bf(acc[i][j][2] + bv4.z * bs);
      o4.w = f2bf(acc[i][j][3] + bv4.w * bs);
      *(ushort4*)&P[(size_t)row_g * DD + col] = o4;
    }
  }
}

// ================= fused flash attention (V pre-transposed, QBLK=128) =================
// 512 threads = 8 waves, each wave owns 16 q-rows. grid (S/128, B*H).
// T14 async-STAGE: tile kt+1's global loads issue right after tile kt's staging
// barriers, hiding HBM latency under the QK^T/softmax/PV compute phase.
__global__ __launch_bounds__(512, 2)
void attn_kernel(const ushort* __restrict__ qb, const ushort* __restrict__ kb,
                 const ushort* __restrict__ vt, const float* __restrict__ relt,
                 const float* __restrict__ amask, ushort* __restrict__ ctxb)
{
  __shared__ ushort Kt[128][72];
  __shared__ ushort Vt[64][136];
  __shared__ ushort Pl[128][136];
  __shared__ float am_lds[512];
  __shared__ float rel_lds[1024];

  const int tid = threadIdx.x, lane = tid & 63, w = tid >> 6;

  int lin = blockIdx.y * gridDim.x + blockIdx.x;        // 0..767
  lin = (lin & 7) * 96 + (lin >> 3);
  const int qt = lin & 3;
  const int bh = lin >> 2;
  const int b = bh / HH, h = bh - b * HH;
  const int fr = lane & 15, fg = lane >> 4;

  am_lds[tid] = (1.0f - amask[b * SS + tid]) * -10000.0f;
  {
    int d0 = tid - 512;
    d0 = max(-128, d0);
    rel_lds[tid] = relt[(d0 + 128) * HH + h];
    int d1 = tid;
    d1 = min(128, d1);
    rel_lds[tid + 512] = relt[(d1 + 128) * HH + h];
  }

  bf16x8 qf[2];
  {
    const int qrow = qt * 128 + w * 16 + fr;
    const ushort* p = qb + ((size_t)(b * SS + qrow) * DD) + h * DHD + fg * 8;
    qf[0] = *(const bf16x8*)p;
    qf[1] = *(const bf16x8*)(p + 32);
  }

  f32x4 o[4];
  float mrow[4], lrow[4];
#pragma unroll
  for (int r = 0; r < 4; ++r) { mrow[r] = -1e30f; lrow[r] = 0.f; }
#pragma unroll
  for (int d = 0; d < 4; ++d) o[d] = f32x4{0.f, 0.f, 0.f, 0.f};

  const int skr = tid >> 2;
  const int shd = (tid & 3) * 16;
  const int vrow = tid >> 3;
  const int vcg  = (tid & 7) * 16;
  const ushort* vgl = vt + ((size_t)bh * DHD + vrow) * SS + vcg;

  const int qg0 = qt * 128 + w * 16;

  int4 kr0, kr1, vr0, vr1;
  auto load_tile = [&](int kt) {
    const size_t gbase = ((size_t)(b * SS + kt * 128 + skr) * DD) + h * DHD + shd;
    kr0 = *(const int4*)(kb + gbase);
    kr1 = *(const int4*)(kb + gbase + 8);
    const ushort* vp = vgl + kt * 128;
    vr0 = *(const int4*)(vp);
    vr1 = *(const int4*)(vp + 8);
  };

  load_tile(0);

  for (int kt = 0; kt < 4; ++kt) {
    __syncthreads();   // previous tile's LDS reads complete
    *(int4*)&Kt[skr][shd]     = kr0;
    *(int4*)&Kt[skr][shd + 8] = kr1;
    *(int4*)&Vt[vrow][vcg]     = vr0;
    *(int4*)&Vt[vrow][vcg + 8] = vr1;
    __syncthreads();   // staging visible

    // issue next tile's loads early — latency hides under this tile's compute
    if (kt + 1 < 4) load_tile(kt + 1);

    float sv[8][4];
    __builtin_amdgcn_s_setprio(1);
#pragma unroll
    for (int kc = 0; kc < 8; ++kc) {
      f32x4 s = f32x4{0.f, 0.f, 0.f, 0.f};
      bf16x8 kf0 = *(const bf16x8*)&Kt[kc * 16 + fr][fg * 8];
      bf16x8 kf1 = *(const bf16x8*)&Kt[kc * 16 + fr][32 + fg * 8];
      s = __builtin_amdgcn_mfma_f32_16x16x32_bf16(qf[0], kf0, s, 0, 0, 0);
      s = __builtin_amdgcn_mfma_f32_16x16x32_bf16(qf[1], kf1, s, 0, 0, 0);
      const int col = kt * 128 + kc * 16 + fr;
      const float am = am_lds[col];
      const int ridx = col - qg0 - fg * 4 + 512;
#pragma unroll
      for (int r = 0; r < 4; ++r)
        sv[kc][r] = s[r] * 0.125f + rel_lds[ridx - r] + am;
    }
    __builtin_amdgcn_s_setprio(0);

    float ef[4];
#pragma unroll
    for (int r = 0; r < 4; ++r) {
      float tmax = sv[0][r];
#pragma unroll
      for (int kc = 1; kc < 8; ++kc) tmax = fmaxf(tmax, sv[kc][r]);
#pragma unroll
      for (int off = 1; off < 16; off <<= 1) tmax = fmaxf(tmax, __shfl_xor(tmax, off));
      const float mnew = fmaxf(mrow[r], tmax);
      ef[r] = __expf(mrow[r] - mnew);
      float psum = 0.f;
      const int prow = w * 16 + fg * 4 + r;
#pragma unroll
      for (int kc = 0; kc < 8; ++kc) {
        float p = __expf(sv[kc][r] - mnew);
        psum += p;
        Pl[prow][kc * 16 + fr] = f2bf(p);
      }
#pragma unroll
      for (int off = 1; off < 16; off <<= 1) psum += __shfl_xor(psum, off);
      lrow[r] = lrow[r] * ef[r] + psum;
      mrow[r] = mnew;
    }
#pragma unroll
    for (int dc = 0; dc < 4; ++dc)
#pragma unroll
      for (int r = 0; r < 4; ++r) o[dc][r] *= ef[r];
    __syncthreads();

    __builtin_amdgcn_s_setprio(1);
#pragma unroll
    for (int dc = 0; dc < 4; ++dc)
#pragma unroll
      for (int ks = 0; ks < 4; ++ks) {
        bf16x8 pf = *(const bf16x8*)&Pl[w * 16 + fr][ks * 32 + fg * 8];
        bf16x8 vf = *(const bf16x8*)&Vt[dc * 16 + fr][ks * 32 + fg * 8];
        o[dc] = __builtin_amdgcn_mfma_f32_16x16x32_bf16(pf, vf, o[dc], 0, 0, 0);
      }
    __builtin_amdgcn_s_setprio(0);
  }

#pragma unroll
  for (int dc = 0; dc < 4; ++dc)
#pragma unroll
    for (int r = 0; r < 4; ++r) {
      const int qg = qt * 128 + w * 16 + fg * 4 + r;
      const float v = o[dc][r] / lrow[r];
      ctxb[((size_t)(b * SS + qg) * DD) + h * DHD + dc * 16 + fr] = f2bf(v);
    }
}

// ================= host launch =================
extern "C" void kernel_launch(void* const* d_in, const int* in_sizes, int n_in,
                              void* d_out, int out_size, void* d_ws, size_t ws_size,
                              hipStream_t stream) {
  const int*   ids   = (const int*)d_in[0];
  const float* amask = (const float*)d_in[1];
  const float* wemb  = (const float*)d_in[2];
  const float* pemb  = (const float*)d_in[3];
  const float* eln_w = (const float*)d_in[4];
  const float* eln_b = (const float*)d_in[5];
  const float* relt  = (const float*)d_in[6];
  const float* Wq    = (const float*)d_in[7];
  const float* bq    = (const float*)d_in[8];
  const float* Wk    = (const float*)d_in[9];
  const float* bk    = (const float*)d_in[10];
  const float* Wv    = (const float*)d_in[11];
  const float* bv    = (const float*)d_in[12];
  const float* Wo    = (const float*)d_in[13];
  const float* bo    = (const float*)d_in[14];
  const float* aln_w = (const float*)d_in[15];
  const float* aln_b = (const float*)d_in[16];
  const float* Wi    = (const float*)d_in[17];
  const float* bi    = (const float*)d_in[18];
  const float* Wd    = (const float*)d_in[19];
  const float* bd    = (const float*)d_in[20];
  const float* oln_w = (const float*)d_in[21];
  const float* oln_b = (const float*)d_in[22];

  size_t off = 0;
  auto carve = [&](size_t bytes) -> void* {
    void* r = (char*)d_ws + off;
    off += (bytes + 255) & ~(size_t)255;
    return r;
  };
  float*  hf     = (float*) carve((size_t)MM * DD * 4);
  ushort* hb     = (ushort*)carve((size_t)MM * DD * 2);
  ushort* qbuf   = (ushort*)carve((size_t)MM * DD * 2);
  ushort* kbuf   = (ushort*)carve((size_t)MM * DD * 2);
  ushort* vbuf   = (ushort*)carve((size_t)MM * DD * 2);   // vT[b][h][d][s]
  ushort* ctxb   = (ushort*)carve((size_t)MM * DD * 2);
  ushort* gout   = (ushort*)carve((size_t)MM * DD * 2);   // split-K partial 0 (bf16)
  ushort* gout2  = (ushort*)carve((size_t)MM * DD * 2);   // split-K partial 1 (bf16)
  ushort* interb = (ushort*)carve((size_t)MM * FF * 2);
  const int PD = DD * DD;
  const int PF = FF * DD;
  ushort* wBded  = (ushort*)carve((size_t)2 * PF * 2);    // Wi,Wd bf16 (dedicated)

  ushort* wA = interb;   // Wq,Wk,Wv,Wo bf16 in interb's dead window

  embed_ln_kernel<<<MM, 256, 0, stream>>>(ids, wemb, pemb, eln_w, eln_b, hf, hb);

  const dim3 gQKV(MM / 128, 3 * (DD / 128));  // 64 x 18
  const dim3 gSK(MM / 128, 2 * (DD / 128));   // 64 x 12 (split-K=2)
  const dim3 gF(MM / 128, FF / 128);          // 64 x 24
  const dim3 gA(SS / 128, BB * HH);           // 4 x 192
  const dim3 gC(PF / 1024, 6);                // 2304 x 6

  for (int l = 0; l < LL; ++l) {
    const size_t wo  = (size_t)l * PD;
    const size_t wio = (size_t)l * PF;

    convw6<<<gC, 256, 0, stream>>>(Wq + wo, Wk + wo, Wv + wo, Wo + wo,
                                   Wi + wio, Wd + wio, wA, wBded, PD, PF);

    gemm_ker<0, true><<<gQKV, 256, 0, stream>>>(hb, wA, wA + PD, wA + 2 * PD,
                                                bq + l * DD, bk + l * DD, bv + l * DD,
                                                qbuf, kbuf, vbuf, DD, DD / 128);

    attn_kernel<<<gA, 512, 0, stream>>>(qbuf, kbuf, vbuf, relt, amask, ctxb);

    gemm_sk<<<gSK, 256, 0, stream>>>(ctxb, wA + 3 * PD, bo + l * DD, gout, gout2, DD);
    add_ln2_kernel<<<MM, 256, 0, stream>>>(hf, gout, gout2,
                                           aln_w + l * DD, aln_b + l * DD, hf, hb);

    gemm_ker<2, false><<<gF, 256, 0, stream>>>(hb, wBded, wBded, wBded,
                                               bi + l * FF, bi + l * FF, bi + l * FF,
                                               interb, interb, interb, DD, FF / 128);
    gemm_sk<<<gSK, 256, 0, stream>>>(interb, wBded + PF, bd + l * DD, gout, gout2, FF);

    float* outp = (l == LL - 1) ? (float*)d_out : hf;
    add_ln2_kernel<<<MM, 256, 0, stream>>>(hf, gout, gout2,
                                           oln_w + l * DD, oln_b + l * DD, outp, hb);
  }
}

// Round 15
// 3036.258 us; speedup vs baseline: 2.5319x; 1.1025x over previous
//
#include <hip/hip_runtime.h>
#include <cstdint>
#include <cstddef>

// ---------------- config ----------------
#define BB 16
#define SS 512
#define DD 768
#define HH 12
#define FF 3072
#define LL 12
#define DHD 64
#define MM (BB*SS)   // 8192 rows

typedef __attribute__((ext_vector_type(8))) short bf16x8;
typedef __attribute__((ext_vector_type(4))) float f32x4;

__device__ __forceinline__ ushort f2bf(float f) {
  union { float f; uint32_t u; } x; x.f = f;
  uint32_t r = x.u + 0x7FFFu + ((x.u >> 16) & 1u);
  return (ushort)(r >> 16);
}
__device__ __forceinline__ float bf2f(ushort u) {
  union { uint32_t u; float f; } x; x.u = (uint32_t)u << 16;
  return x.f;
}

__device__ __forceinline__ void glds16(const ushort* g, ushort* l) {
  __builtin_amdgcn_global_load_lds((__attribute__((address_space(1))) void*)g,
                                   (__attribute__((address_space(3))) void*)l,
                                   16, 0, 0);
}

__device__ __forceinline__ float gelu_t(float v) {
  // v * sigmoid(2y), y = 0.79788456(v + 0.044715 v^3); == tanh-gelu
  const float v2 = v * v;
  const float u = v * (-1.5957691216f - 0.0713548163f * v2);   // -2y
  return v / (1.f + __expf(u));
}

// ================= weight f32 -> bf16 conversion (6 tensors, one dispatch) ==========
__global__ __launch_bounds__(256)
void convw6(const float* __restrict__ s0, const float* __restrict__ s1,
            const float* __restrict__ s2, const float* __restrict__ s3,
            const float* __restrict__ s4, const float* __restrict__ s5,
            ushort* __restrict__ dA, ushort* __restrict__ dB, int perD, int perF)
{
  const int y = blockIdx.y;
  const int per = (y < 4) ? perD : perF;
  const int i = (blockIdx.x * 256 + threadIdx.x) * 4;
  if (i >= per) return;
  const float* s = y == 0 ? s0 : y == 1 ? s1 : y == 2 ? s2 : y == 3 ? s3 : y == 4 ? s4 : s5;
  ushort* dst = (y < 4) ? (dA + (size_t)y * perD) : (dB + (size_t)(y - 4) * perF);
  const float4 v = *(const float4*)(s + i);
  ushort4 o;
  o.x = f2bf(v.x); o.y = f2bf(v.y); o.z = f2bf(v.z); o.w = f2bf(v.w);
  *(ushort4*)(dst + i) = o;
}

// ================= embedding + LayerNorm =================
__global__ __launch_bounds__(256)
void embed_ln_kernel(const int* __restrict__ ids, const float* __restrict__ wemb,
                     const float* __restrict__ pemb, const float* __restrict__ g,
                     const float* __restrict__ bt, float* __restrict__ hf,
                     ushort* __restrict__ hb)
{
  const int row = blockIdx.x;
  const int s = row & (SS - 1);
  const int id = ids[row];
  const float* wp = wemb + (size_t)id * DD;
  const float* pp = pemb + (size_t)s * DD;
  const int tid = threadIdx.x;
  float v[3]; float sum = 0.f, sq = 0.f;
#pragma unroll
  for (int j = 0; j < 3; ++j) {
    int e = tid + j * 256;
    v[j] = wp[e] + pp[e];
    sum += v[j]; sq += v[j] * v[j];
  }
  __shared__ float red[2][4];
#pragma unroll
  for (int off = 32; off >= 1; off >>= 1) { sum += __shfl_xor(sum, off); sq += __shfl_xor(sq, off); }
  const int lane = tid & 63, wid = tid >> 6;
  if (lane == 0) { red[0][wid] = sum; red[1][wid] = sq; }
  __syncthreads();
  sum = red[0][0] + red[0][1] + red[0][2] + red[0][3];
  sq  = red[1][0] + red[1][1] + red[1][2] + red[1][3];
  const float mean = sum * (1.f / DD);
  const float var  = sq  * (1.f / DD) - mean * mean;
  const float rstd = rsqrtf(var + 1e-12f);
  const size_t base = (size_t)row * DD;
#pragma unroll
  for (int j = 0; j < 3; ++j) {
    int e = tid + j * 256;
    float o = (v[j] - mean) * rstd * g[e] + bt[e];
    hf[base + e] = o;
    hb[base + e] = f2bf(o);
  }
}

// ================= residual + two bf16 split-K partials + LayerNorm =================
__global__ __launch_bounds__(256)
void add_ln2_kernel(const float* __restrict__ res, const ushort* __restrict__ p0,
                    const ushort* __restrict__ p1, const float* __restrict__ g,
                    const float* __restrict__ bt, float* __restrict__ hf,
                    ushort* __restrict__ hb)
{
  const int row = blockIdx.x;
  const int tid = threadIdx.x;
  const size_t base = (size_t)row * DD;
  float v[3]; float sum = 0.f, sq = 0.f;
#pragma unroll
  for (int j = 0; j < 3; ++j) {
    int e = tid + j * 256;
    v[j] = res[base + e] + bf2f(p0[base + e]) + bf2f(p1[base + e]);
    sum += v[j]; sq += v[j] * v[j];
  }
  __shared__ float red[2][4];
#pragma unroll
  for (int off = 32; off >= 1; off >>= 1) { sum += __shfl_xor(sum, off); sq += __shfl_xor(sq, off); }
  const int lane = tid & 63, wid = tid >> 6;
  if (lane == 0) { red[0][wid] = sum; red[1][wid] = sq; }
  __syncthreads();
  sum = red[0][0] + red[0][1] + red[0][2] + red[0][3];
  sq  = red[1][0] + red[1][1] + red[1][2] + red[1][3];
  const float mean = sum * (1.f / DD);
  const float var  = sq  * (1.f / DD) - mean * mean;
  const float rstd = rsqrtf(var + 1e-12f);
#pragma unroll
  for (int j = 0; j < 3; ++j) {
    int e = tid + j * 256;
    float o = (v[j] - mean) * rstd * g[e] + bt[e];
    hf[base + e] = o;
    hb[base + e] = f2bf(o);
  }
}

// ================= GEMM: C[M,N] = A[M,K](bf16) @ Bw[N,K](bf16)^T + bias =================
// m97 schedule: 128x128 tile, BK=32, double-buffered (32KB -> 4 blocks/CU),
// XOR-swizzled staging (0 bank conflicts), swapped-operand MFMA, vectorized epilogue.
// L2-locality mapping: XCD x owns bm-slab [x*8, x*8+8) across ALL bn -> the A-slab
// (~1.6MB) stays L2-resident; B panels stream via L3. (Old mapping gave each XCD
// 3 bn columns x all 64 bm -> A re-streamed 12.6MB through 4MB L2 every sweep.)
// NOTE: do NOT raise the occupancy bound past 4 — at 5 the allocator drops below
// 64 VGPR, spills acc to scratch, and WRITE_SIZE explodes 49->713MB (round 13).
// EPI 0: bf16 out; 2: bf16 out + gelu. TRV: sub==2 writes vT[b][h][d][s].
template<int EPI, bool TRV>
__global__ __launch_bounds__(256, 4)
void gemm_ker(const ushort* __restrict__ A,
              const ushort* __restrict__ B0, const ushort* __restrict__ B1,
              const ushort* __restrict__ B2,
              const float* __restrict__ bias0, const float* __restrict__ bias1,
              const float* __restrict__ bias2,
              void* __restrict__ C0, void* __restrict__ C1, void* __restrict__ C2,
              int Kdim, int nblk)
{
  __shared__ ushort As[2][128 * 32];
  __shared__ ushort Bs[2][128 * 32];

  // physical XCD = linear id & 7 (round-robin dispatch); rank = id>>3.
  // bm = x*8 + (r&7): 8-block bm slab per XCD; bn sweeps within the slab.
  // Bijective: total/8 divisible by 8 for all grids (144/192/96).
  const int id = blockIdx.y * gridDim.x + blockIdx.x;
  const int x = id & 7;
  const int r = id >> 3;
  const int bm = x * 8 + (r & 7);
  const int bnAll = r >> 3;
  const int sub = bnAll / nblk;
  const int bn = bnAll - sub * nblk;

  const ushort* Bw  = sub == 0 ? B0 : (sub == 1 ? B1 : B2);
  const float* bias = sub == 0 ? bias0 : (sub == 1 ? bias1 : bias2);
  const int Ndim = nblk * 128;

  const int tid = threadIdx.x;
  const int l = tid & 63, w = tid >> 6;
  const int wm = w >> 1, wn = w & 1;
  const int fr = l & 15, fg = l >> 4;

  const int srow_in = l >> 2;
  const int gks = ((l & 3) ^ ((l >> 3) & 3)) * 8;
  const ushort* Agl0 = A  + (size_t)(bm * 128 + w * 16 + srow_in) * Kdim + gks;
  const ushort* Agl1 = Agl0 + (size_t)64 * Kdim;
  const ushort* Bgl0 = Bw + (size_t)(bn * 128 + w * 16 + srow_in) * Kdim + gks;
  const ushort* Bgl1 = Bgl0 + (size_t)64 * Kdim;

  auto stage = [&](int b, int kt) {
    const int ko = kt * 32;
    ushort* al = &As[b][w * 64 * 8];
    ushort* bl = &Bs[b][w * 64 * 8];
    glds16(Agl0 + ko, al);
    glds16(Agl1 + ko, al + 256 * 8);
    glds16(Bgl0 + ko, bl);
    glds16(Bgl1 + ko, bl + 256 * 8);
  };

  const int se = (fg ^ ((fr >> 1) & 3)) * 8;

  f32x4 acc[4][4];
#pragma unroll
  for (int i = 0; i < 4; ++i)
#pragma unroll
    for (int j = 0; j < 4; ++j) acc[i][j] = f32x4{0.f, 0.f, 0.f, 0.f};

  stage(0, 0);
  __syncthreads();

  const int nk = Kdim >> 5;
  int cur = 0;
  for (int kt = 0; kt < nk; ++kt) {
    if (kt + 1 < nk) stage(cur ^ 1, kt + 1);

    bf16x8 af[4], bfv[4];
#pragma unroll
    for (int i = 0; i < 4; ++i)
      af[i]  = *(const bf16x8*)&As[cur][(wm * 64 + i * 16 + fr) * 32 + se];
#pragma unroll
    for (int j = 0; j < 4; ++j)
      bfv[j] = *(const bf16x8*)&Bs[cur][(wn * 64 + j * 16 + fr) * 32 + se];

    __builtin_amdgcn_s_setprio(1);
#pragma unroll
    for (int i = 0; i < 4; ++i)
#pragma unroll
      for (int j = 0; j < 4; ++j)
        acc[i][j] = __builtin_amdgcn_mfma_f32_16x16x32_bf16(bfv[j], af[i], acc[i][j], 0, 0, 0);
    __builtin_amdgcn_s_setprio(0);

    __syncthreads();
    cur ^= 1;
  }

#pragma unroll
  for (int i = 0; i < 4; ++i) {
    const int row_g = bm * 128 + wm * 64 + i * 16 + fr;
#pragma unroll
    for (int j = 0; j < 4; ++j) {
      const int col = bn * 128 + wn * 64 + j * 16 + fg * 4;
      const float4 bv4 = *(const float4*)&bias[col];
      const float v0 = acc[i][j][0] + bv4.x;
      const float v1 = acc[i][j][1] + bv4.y;
      const float v2 = acc[i][j][2] + bv4.z;
      const float v3 = acc[i][j][3] + bv4.w;
      if (TRV && sub == 2) {
        const int b_ = row_g >> 9, s_ = row_g & 511;
        const int h_ = col >> 6, d0 = col & 63;
        ushort* vp = (ushort*)C2 + (((size_t)(b_ * HH + h_) * DHD + d0) * SS + s_);
        vp[0] = f2bf(v0); vp[SS] = f2bf(v1); vp[2 * SS] = f2bf(v2); vp[3 * SS] = f2bf(v3);
      } else if (EPI == 2) {
        ushort4 o4;
        o4.x = f2bf(gelu_t(v0)); o4.y = f2bf(gelu_t(v1));
        o4.z = f2bf(gelu_t(v2)); o4.w = f2bf(gelu_t(v3));
        *(ushort4*)&((ushort*)C0)[(size_t)row_g * Ndim + col] = o4;
      } else {
        void* Cout = sub == 0 ? C0 : (sub == 1 ? C1 : C2);
        ushort4 o4;
        o4.x = f2bf(v0); o4.y = f2bf(v1); o4.z = f2bf(v2); o4.w = f2bf(v3);
        *(ushort4*)&((ushort*)Cout)[(size_t)row_g * Ndim + col] = o4;
      }
    }
  }
}

// ================= split-K=2 GEMM for N=768 (O-proj, Wd) — bf16 partials =================
// grid (64, 12): rest encodes bn (6) x sk (2). bf16 partials to P0/P1; bias in sk==0.
__global__ __launch_bounds__(256, 4)
void gemm_sk(const ushort* __restrict__ A, const ushort* __restrict__ Bw,
             const float* __restrict__ bias, ushort* __restrict__ P0,
             ushort* __restrict__ P1, int Kdim)
{
  __shared__ ushort As[2][128 * 32];
  __shared__ ushort Bs[2][128 * 32];

  // same L2-locality bm-slab mapping (total=768, rank<96, 96%8==0: bijective)
  const int id = blockIdx.y * gridDim.x + blockIdx.x;
  const int x = id & 7;
  const int r = id >> 3;
  const int bm = x * 8 + (r & 7);
  const int rest = r >> 3;           // 0..11
  const int bn = rest >> 1;
  const int sk = rest & 1;

  const int Kh = Kdim >> 1;

  const int tid = threadIdx.x;
  const int l = tid & 63, w = tid >> 6;
  const int wm = w >> 1, wn = w & 1;
  const int fr = l & 15, fg = l >> 4;

  const int srow_in = l >> 2;
  const int gks = ((l & 3) ^ ((l >> 3) & 3)) * 8;
  const ushort* Agl0 = A  + (size_t)(bm * 128 + w * 16 + srow_in) * Kdim + sk * Kh + gks;
  const ushort* Agl1 = Agl0 + (size_t)64 * Kdim;
  const ushort* Bgl0 = Bw + (size_t)(bn * 128 + w * 16 + srow_in) * Kdim + sk * Kh + gks;
  const ushort* Bgl1 = Bgl0 + (size_t)64 * Kdim;

  auto stage = [&](int b, int kt) {
    const int ko = kt * 32;
    ushort* al = &As[b][w * 64 * 8];
    ushort* bl = &Bs[b][w * 64 * 8];
    glds16(Agl0 + ko, al);
    glds16(Agl1 + ko, al + 256 * 8);
    glds16(Bgl0 + ko, bl);
    glds16(Bgl1 + ko, bl + 256 * 8);
  };

  const int se = (fg ^ ((fr >> 1) & 3)) * 8;

  f32x4 acc[4][4];
#pragma unroll
  for (int i = 0; i < 4; ++i)
#pragma unroll
    for (int j = 0; j < 4; ++j) acc[i][j] = f32x4{0.f, 0.f, 0.f, 0.f};

  stage(0, 0);
  __syncthreads();

  const int nk = Kh >> 5;
  int cur = 0;
  for (int kt = 0; kt < nk; ++kt) {
    if (kt + 1 < nk) stage(cur ^ 1, kt + 1);

    bf16x8 af[4], bfv[4];
#pragma unroll
    for (int i = 0; i < 4; ++i)
      af[i]  = *(const bf16x8*)&As[cur][(wm * 64 + i * 16 + fr) * 32 + se];
#pragma unroll
    for (int j = 0; j < 4; ++j)
      bfv[j] = *(const bf16x8*)&Bs[cur][(wn * 64 + j * 16 + fr) * 32 + se];

    __builtin_amdgcn_s_setprio(1);
#pragma unroll
    for (int i = 0; i < 4; ++i)
#pragma unroll
      for (int j = 0; j < 4; ++j)
        acc[i][j] = __builtin_amdgcn_mfma_f32_16x16x32_bf16(bfv[j], af[i], acc[i][j], 0, 0, 0);
    __builtin_amdgcn_s_setprio(0);

    __syncthreads();
    cur ^= 1;
  }

  ushort* P = sk ? P1 : P0;
  const float bs = sk ? 0.f : 1.f;
#pragma unroll
  for (int i = 0; i < 4; ++i) {
    const int row_g = bm * 128 + wm * 64 + i * 16 + fr;
#pragma unroll
    for (int j = 0; j < 4; ++j) {
      const int col = bn * 128 + wn * 64 + j * 16 + fg * 4;
      const float4 bv4 = *(const float4*)&bias[col];
      ushort4 o4;
      o4.x = f2bf(acc[i][j][0] + bv4.x * bs);
      o4.y = f2bf(acc[i][j][1] + bv4.y * bs);
      o4.z = f2bf(acc[i][j][2] + bv4.z * bs);
      o4.w = f2bf(acc[i][j][3] + bv4.w * bs);
      *(ushort4*)&P[(size_t)row_g * DD + col] = o4;
    }
  }
}

// ================= fused flash attention (V pre-transposed, QBLK=128) =================
// 512 threads = 8 waves, each wave owns 16 q-rows. grid (S/128, B*H).
// T14 async-STAGE: tile kt+1's global loads issue right after tile kt's staging
// barriers, hiding HBM latency under the QK^T/softmax/PV compute phase.
__global__ __launch_bounds__(512, 2)
void attn_kernel(const ushort* __restrict__ qb, const ushort* __restrict__ kb,
                 const ushort* __restrict__ vt, const float* __restrict__ relt,
                 const float* __restrict__ amask, ushort* __restrict__ ctxb)
{
  __shared__ ushort Kt[128][72];
  __shared__ ushort Vt[64][136];
  __shared__ ushort Pl[128][136];
  __shared__ float am_lds[512];
  __shared__ float rel_lds[1024];

  const int tid = threadIdx.x, lane = tid & 63, w = tid >> 6;

  int lin = blockIdx.y * gridDim.x + blockIdx.x;        // 0..767
  lin = (lin & 7) * 96 + (lin >> 3);
  const int qt = lin & 3;
  const int bh = lin >> 2;
  const int b = bh / HH, h = bh - b * HH;
  const int fr = lane & 15, fg = lane >> 4;

  am_lds[tid] = (1.0f - amask[b * SS + tid]) * -10000.0f;
  {
    int d0 = tid - 512;
    d0 = max(-128, d0);
    rel_lds[tid] = relt[(d0 + 128) * HH + h];
    int d1 = tid;
    d1 = min(128, d1);
    rel_lds[tid + 512] = relt[(d1 + 128) * HH + h];
  }

  bf16x8 qf[2];
  {
    const int qrow = qt * 128 + w * 16 + fr;
    const ushort* p = qb + ((size_t)(b * SS + qrow) * DD) + h * DHD + fg * 8;
    qf[0] = *(const bf16x8*)p;
    qf[1] = *(const bf16x8*)(p + 32);
  }

  f32x4 o[4];
  float mrow[4], lrow[4];
#pragma unroll
  for (int r = 0; r < 4; ++r) { mrow[r] = -1e30f; lrow[r] = 0.f; }
#pragma unroll
  for (int d = 0; d < 4; ++d) o[d] = f32x4{0.f, 0.f, 0.f, 0.f};

  const int skr = tid >> 2;
  const int shd = (tid & 3) * 16;
  const int vrow = tid >> 3;
  const int vcg  = (tid & 7) * 16;
  const ushort* vgl = vt + ((size_t)bh * DHD + vrow) * SS + vcg;

  const int qg0 = qt * 128 + w * 16;

  int4 kr0, kr1, vr0, vr1;
  auto load_tile = [&](int kt) {
    const size_t gbase = ((size_t)(b * SS + kt * 128 + skr) * DD) + h * DHD + shd;
    kr0 = *(const int4*)(kb + gbase);
    kr1 = *(const int4*)(kb + gbase + 8);
    const ushort* vp = vgl + kt * 128;
    vr0 = *(const int4*)(vp);
    vr1 = *(const int4*)(vp + 8);
  };

  load_tile(0);

  for (int kt = 0; kt < 4; ++kt) {
    __syncthreads();   // previous tile's LDS reads complete
    *(int4*)&Kt[skr][shd]     = kr0;
    *(int4*)&Kt[skr][shd + 8] = kr1;
    *(int4*)&Vt[vrow][vcg]     = vr0;
    *(int4*)&Vt[vrow][vcg + 8] = vr1;
    __syncthreads();   // staging visible

    // issue next tile's loads early — latency hides under this tile's compute
    if (kt + 1 < 4) load_tile(kt + 1);

    float sv[8][4];
    __builtin_amdgcn_s_setprio(1);
#pragma unroll
    for (int kc = 0; kc < 8; ++kc) {
      f32x4 s = f32x4{0.f, 0.f, 0.f, 0.f};
      bf16x8 kf0 = *(const bf16x8*)&Kt[kc * 16 + fr][fg * 8];
      bf16x8 kf1 = *(const bf16x8*)&Kt[kc * 16 + fr][32 + fg * 8];
      s = __builtin_amdgcn_mfma_f32_16x16x32_bf16(qf[0], kf0, s, 0, 0, 0);
      s = __builtin_amdgcn_mfma_f32_16x16x32_bf16(qf[1], kf1, s, 0, 0, 0);
      const int col = kt * 128 + kc * 16 + fr;
      const float am = am_lds[col];
      const int ridx = col - qg0 - fg * 4 + 512;
#pragma unroll
      for (int r = 0; r < 4; ++r)
        sv[kc][r] = s[r] * 0.125f + rel_lds[ridx - r] + am;
    }
    __builtin_amdgcn_s_setprio(0);

    float ef[4];
#pragma unroll
    for (int r = 0; r < 4; ++r) {
      float tmax = sv[0][r];
#pragma unroll
      for (int kc = 1; kc < 8; ++kc) tmax = fmaxf(tmax, sv[kc][r]);
#pragma unroll
      for (int off = 1; off < 16; off <<= 1) tmax = fmaxf(tmax, __shfl_xor(tmax, off));
      const float mnew = fmaxf(mrow[r], tmax);
      ef[r] = __expf(mrow[r] - mnew);
      float psum = 0.f;
      const int prow = w * 16 + fg * 4 + r;
#pragma unroll
      for (int kc = 0; kc < 8; ++kc) {
        float p = __expf(sv[kc][r] - mnew);
        psum += p;
        Pl[prow][kc * 16 + fr] = f2bf(p);
      }
#pragma unroll
      for (int off = 1; off < 16; off <<= 1) psum += __shfl_xor(psum, off);
      lrow[r] = lrow[r] * ef[r] + psum;
      mrow[r] = mnew;
    }
#pragma unroll
    for (int dc = 0; dc < 4; ++dc)
#pragma unroll
      for (int r = 0; r < 4; ++r) o[dc][r] *= ef[r];
    __syncthreads();

    __builtin_amdgcn_s_setprio(1);
#pragma unroll
    for (int dc = 0; dc < 4; ++dc)
#pragma unroll
      for (int ks = 0; ks < 4; ++ks) {
        bf16x8 pf = *(const bf16x8*)&Pl[w * 16 + fr][ks * 32 + fg * 8];
        bf16x8 vf = *(const bf16x8*)&Vt[dc * 16 + fr][ks * 32 + fg * 8];
        o[dc] = __builtin_amdgcn_mfma_f32_16x16x32_bf16(pf, vf, o[dc], 0, 0, 0);
      }
    __builtin_amdgcn_s_setprio(0);
  }

#pragma unroll
  for (int dc = 0; dc < 4; ++dc)
#pragma unroll
    for (int r = 0; r < 4; ++r) {
      const int qg = qt * 128 + w * 16 + fg * 4 + r;
      const float v = o[dc][r] / lrow[r];
      ctxb[((size_t)(b * SS + qg) * DD) + h * DHD + dc * 16 + fr] = f2bf(v);
    }
}

// ================= host launch =================
extern "C" void kernel_launch(void* const* d_in, const int* in_sizes, int n_in,
                              void* d_out, int out_size, void* d_ws, size_t ws_size,
                              hipStream_t stream) {
  const int*   ids   = (const int*)d_in[0];
  const float* amask = (const float*)d_in[1];
  const float* wemb  = (const float*)d_in[2];
  const float* pemb  = (const float*)d_in[3];
  const float* eln_w = (const float*)d_in[4];
  const float* eln_b = (const float*)d_in[5];
  const float* relt  = (const float*)d_in[6];
  const float* Wq    = (const float*)d_in[7];
  const float* bq    = (const float*)d_in[8];
  const float* Wk    = (const float*)d_in[9];
  const float* bk    = (const float*)d_in[10];
  const float* Wv    = (const float*)d_in[11];
  const float* bv    = (const float*)d_in[12];
  const float* Wo    = (const float*)d_in[13];
  const float* bo    = (const float*)d_in[14];
  const float* aln_w = (const float*)d_in[15];
  const float* aln_b = (const float*)d_in[16];
  const float* Wi    = (const float*)d_in[17];
  const float* bi    = (const float*)d_in[18];
  const float* Wd    = (const float*)d_in[19];
  const float* bd    = (const float*)d_in[20];
  const float* oln_w = (const float*)d_in[21];
  const float* oln_b = (const float*)d_in[22];

  size_t off = 0;
  auto carve = [&](size_t bytes) -> void* {
    void* r = (char*)d_ws + off;
    off += (bytes + 255) & ~(size_t)255;
    return r;
  };
  float*  hf     = (float*) carve((size_t)MM * DD * 4);
  ushort* hb     = (ushort*)carve((size_t)MM * DD * 2);
  ushort* qbuf   = (ushort*)carve((size_t)MM * DD * 2);
  ushort* kbuf   = (ushort*)carve((size_t)MM * DD * 2);
  ushort* vbuf   = (ushort*)carve((size_t)MM * DD * 2);   // vT[b][h][d][s]
  ushort* ctxb   = (ushort*)carve((size_t)MM * DD * 2);
  ushort* gout   = (ushort*)carve((size_t)MM * DD * 2);   // split-K partial 0 (bf16)
  ushort* gout2  = (ushort*)carve((size_t)MM * DD * 2);   // split-K partial 1 (bf16)
  ushort* interb = (ushort*)carve((size_t)MM * FF * 2);
  const int PD = DD * DD;
  const int PF = FF * DD;
  ushort* wBded  = (ushort*)carve((size_t)2 * PF * 2);    // Wi,Wd bf16 (dedicated)

  ushort* wA = interb;   // Wq,Wk,Wv,Wo bf16 in interb's dead window

  embed_ln_kernel<<<MM, 256, 0, stream>>>(ids, wemb, pemb, eln_w, eln_b, hf, hb);

  const dim3 gQKV(MM / 128, 3 * (DD / 128));  // 64 x 18
  const dim3 gSK(MM / 128, 2 * (DD / 128));   // 64 x 12 (split-K=2)
  const dim3 gF(MM / 128, FF / 128);          // 64 x 24
  const dim3 gA(SS / 128, BB * HH);           // 4 x 192
  const dim3 gC(PF / 1024, 6);                // 2304 x 6

  for (int l = 0; l < LL; ++l) {
    const size_t wo  = (size_t)l * PD;
    const size_t wio = (size_t)l * PF;

    convw6<<<gC, 256, 0, stream>>>(Wq + wo, Wk + wo, Wv + wo, Wo + wo,
                                   Wi + wio, Wd + wio, wA, wBded, PD, PF);

    gemm_ker<0, true><<<gQKV, 256, 0, stream>>>(hb, wA, wA + PD, wA + 2 * PD,
                                                bq + l * DD, bk + l * DD, bv + l * DD,
                                                qbuf, kbuf, vbuf, DD, DD / 128);

    attn_kernel<<<gA, 512, 0, stream>>>(qbuf, kbuf, vbuf, relt, amask, ctxb);

    gemm_sk<<<gSK, 256, 0, stream>>>(ctxb, wA + 3 * PD, bo + l * DD, gout, gout2, DD);
    add_ln2_kernel<<<MM, 256, 0, stream>>>(hf, gout, gout2,
                                           aln_w + l * DD, aln_b + l * DD, hf, hb);

    gemm_ker<2, false><<<gF, 256, 0, stream>>>(hb, wBded, wBded, wBded,
                                               bi + l * FF, bi + l * FF, bi + l * FF,
                                               interb, interb, interb, DD, FF / 128);
    gemm_sk<<<gSK, 256, 0, stream>>>(interb, wBded + PF, bd + l * DD, gout, gout2, FF);

    float* outp = (l == LL - 1) ? (float*)d_out : hf;
    add_ln2_kernel<<<MM, 256, 0, stream>>>(hf, gout, gout2,
                                           oln_w + l * DD, oln_b + l * DD, outp, hb);
  }
}

// Round 16
// 2989.750 us; speedup vs baseline: 2.5713x; 1.0156x over previous
//
#include <hip/hip_runtime.h>
#include <hip/hip_bf16.h>
#include <cstdint>
#include <cstddef>

// ---------------- config ----------------
#define BB 16
#define SS 512
#define DD 768
#define HH 12
#define FF 3072
#define LL 12
#define DHD 64
#define MM (BB*SS)   // 8192 rows

typedef __attribute__((ext_vector_type(8))) short bf16x8;
typedef __attribute__((ext_vector_type(4))) float f32x4;

// hardware RNE conversion — compiler lowers pairs to v_cvt_pk_bf16_f32
// (bit-twiddle version blocked that and cost 4-5 VALU each; m240)
__device__ __forceinline__ ushort f2bf(float f) {
  return __bfloat16_as_ushort(__float2bfloat16(f));
}
__device__ __forceinline__ float bf2f(ushort u) {
  union { uint32_t u; float f; } x; x.u = (uint32_t)u << 16;
  return x.f;
}

__device__ __forceinline__ void glds16(const ushort* g, ushort* l) {
  __builtin_amdgcn_global_load_lds((__attribute__((address_space(1))) void*)g,
                                   (__attribute__((address_space(3))) void*)l,
                                   16, 0, 0);
}

__device__ __forceinline__ float gelu_t(float v) {
  // v * sigmoid(2y), y = 0.79788456(v + 0.044715 v^3); == tanh-gelu
  const float v2 = v * v;
  const float u = v * (-1.5957691216f - 0.0713548163f * v2);   // -2y
  return v / (1.f + __expf(u));
}

// ================= weight f32 -> bf16 conversion (6 tensors, one dispatch) ==========
__global__ __launch_bounds__(256)
void convw6(const float* __restrict__ s0, const float* __restrict__ s1,
            const float* __restrict__ s2, const float* __restrict__ s3,
            const float* __restrict__ s4, const float* __restrict__ s5,
            ushort* __restrict__ dA, ushort* __restrict__ dB, int perD, int perF)
{
  const int y = blockIdx.y;
  const int per = (y < 4) ? perD : perF;
  const int i = (blockIdx.x * 256 + threadIdx.x) * 4;
  if (i >= per) return;
  const float* s = y == 0 ? s0 : y == 1 ? s1 : y == 2 ? s2 : y == 3 ? s3 : y == 4 ? s4 : s5;
  ushort* dst = (y < 4) ? (dA + (size_t)y * perD) : (dB + (size_t)(y - 4) * perF);
  const float4 v = *(const float4*)(s + i);
  ushort4 o;
  o.x = f2bf(v.x); o.y = f2bf(v.y); o.z = f2bf(v.z); o.w = f2bf(v.w);
  *(ushort4*)(dst + i) = o;
}

// ================= embedding + LayerNorm =================
__global__ __launch_bounds__(256)
void embed_ln_kernel(const int* __restrict__ ids, const float* __restrict__ wemb,
                     const float* __restrict__ pemb, const float* __restrict__ g,
                     const float* __restrict__ bt, float* __restrict__ hf,
                     ushort* __restrict__ hb)
{
  const int row = blockIdx.x;
  const int s = row & (SS - 1);
  const int id = ids[row];
  const float* wp = wemb + (size_t)id * DD;
  const float* pp = pemb + (size_t)s * DD;
  const int tid = threadIdx.x;
  float v[3]; float sum = 0.f, sq = 0.f;
#pragma unroll
  for (int j = 0; j < 3; ++j) {
    int e = tid + j * 256;
    v[j] = wp[e] + pp[e];
    sum += v[j]; sq += v[j] * v[j];
  }
  __shared__ float red[2][4];
#pragma unroll
  for (int off = 32; off >= 1; off >>= 1) { sum += __shfl_xor(sum, off); sq += __shfl_xor(sq, off); }
  const int lane = tid & 63, wid = tid >> 6;
  if (lane == 0) { red[0][wid] = sum; red[1][wid] = sq; }
  __syncthreads();
  sum = red[0][0] + red[0][1] + red[0][2] + red[0][3];
  sq  = red[1][0] + red[1][1] + red[1][2] + red[1][3];
  const float mean = sum * (1.f / DD);
  const float var  = sq  * (1.f / DD) - mean * mean;
  const float rstd = rsqrtf(var + 1e-12f);
  const size_t base = (size_t)row * DD;
#pragma unroll
  for (int j = 0; j < 3; ++j) {
    int e = tid + j * 256;
    float o = (v[j] - mean) * rstd * g[e] + bt[e];
    hf[base + e] = o;
    hb[base + e] = f2bf(o);
  }
}

// ================= residual + two bf16 split-K partials + LayerNorm =================
__global__ __launch_bounds__(256)
void add_ln2_kernel(const float* __restrict__ res, const ushort* __restrict__ p0,
                    const ushort* __restrict__ p1, const float* __restrict__ g,
                    const float* __restrict__ bt, float* __restrict__ hf,
                    ushort* __restrict__ hb)
{
  const int row = blockIdx.x;
  const int tid = threadIdx.x;
  const size_t base = (size_t)row * DD;
  float v[3]; float sum = 0.f, sq = 0.f;
#pragma unroll
  for (int j = 0; j < 3; ++j) {
    int e = tid + j * 256;
    v[j] = res[base + e] + bf2f(p0[base + e]) + bf2f(p1[base + e]);
    sum += v[j]; sq += v[j] * v[j];
  }
  __shared__ float red[2][4];
#pragma unroll
  for (int off = 32; off >= 1; off >>= 1) { sum += __shfl_xor(sum, off); sq += __shfl_xor(sq, off); }
  const int lane = tid & 63, wid = tid >> 6;
  if (lane == 0) { red[0][wid] = sum; red[1][wid] = sq; }
  __syncthreads();
  sum = red[0][0] + red[0][1] + red[0][2] + red[0][3];
  sq  = red[1][0] + red[1][1] + red[1][2] + red[1][3];
  const float mean = sum * (1.f / DD);
  const float var  = sq  * (1.f / DD) - mean * mean;
  const float rstd = rsqrtf(var + 1e-12f);
#pragma unroll
  for (int j = 0; j < 3; ++j) {
    int e = tid + j * 256;
    float o = (v[j] - mean) * rstd * g[e] + bt[e];
    hf[base + e] = o;
    hb[base + e] = f2bf(o);
  }
}

// ================= GEMM: C[M,N] = A[M,K](bf16) @ Bw[N,K](bf16)^T + bias =================
// m97 schedule: 128x128 tile, BK=32, double-buffered (32KB -> 4 blocks/CU),
// XOR-swizzled staging (0 bank conflicts), swapped-operand MFMA, vectorized epilogue.
// L2-locality mapping: XCD x owns bm-slab [x*8, x*8+8) across ALL bn (FETCH 115->30MB).
// NOTE: do NOT raise the occupancy bound past 4 — at 5 the allocator drops below
// 64 VGPR, spills acc to scratch, and WRITE_SIZE explodes 49->713MB (round 13).
// EPI 0: bf16 out; 2: bf16 out + gelu. TRV: sub==2 writes vT[b][h][d][s].
template<int EPI, bool TRV>
__global__ __launch_bounds__(256, 4)
void gemm_ker(const ushort* __restrict__ A,
              const ushort* __restrict__ B0, const ushort* __restrict__ B1,
              const ushort* __restrict__ B2,
              const float* __restrict__ bias0, const float* __restrict__ bias1,
              const float* __restrict__ bias2,
              void* __restrict__ C0, void* __restrict__ C1, void* __restrict__ C2,
              int Kdim, int nblk)
{
  __shared__ ushort As[2][128 * 32];
  __shared__ ushort Bs[2][128 * 32];

  const int id = blockIdx.y * gridDim.x + blockIdx.x;
  const int x = id & 7;
  const int r = id >> 3;
  const int bm = x * 8 + (r & 7);
  const int bnAll = r >> 3;
  const int sub = bnAll / nblk;
  const int bn = bnAll - sub * nblk;

  const ushort* Bw  = sub == 0 ? B0 : (sub == 1 ? B1 : B2);
  const float* bias = sub == 0 ? bias0 : (sub == 1 ? bias1 : bias2);
  const int Ndim = nblk * 128;

  const int tid = threadIdx.x;
  const int l = tid & 63, w = tid >> 6;
  const int wm = w >> 1, wn = w & 1;
  const int fr = l & 15, fg = l >> 4;

  const int srow_in = l >> 2;
  const int gks = ((l & 3) ^ ((l >> 3) & 3)) * 8;
  const ushort* Agl0 = A  + (size_t)(bm * 128 + w * 16 + srow_in) * Kdim + gks;
  const ushort* Agl1 = Agl0 + (size_t)64 * Kdim;
  const ushort* Bgl0 = Bw + (size_t)(bn * 128 + w * 16 + srow_in) * Kdim + gks;
  const ushort* Bgl1 = Bgl0 + (size_t)64 * Kdim;

  auto stage = [&](int b, int kt) {
    const int ko = kt * 32;
    ushort* al = &As[b][w * 64 * 8];
    ushort* bl = &Bs[b][w * 64 * 8];
    glds16(Agl0 + ko, al);
    glds16(Agl1 + ko, al + 256 * 8);
    glds16(Bgl0 + ko, bl);
    glds16(Bgl1 + ko, bl + 256 * 8);
  };

  const int se = (fg ^ ((fr >> 1) & 3)) * 8;

  f32x4 acc[4][4];
#pragma unroll
  for (int i = 0; i < 4; ++i)
#pragma unroll
    for (int j = 0; j < 4; ++j) acc[i][j] = f32x4{0.f, 0.f, 0.f, 0.f};

  stage(0, 0);
  __syncthreads();

  const int nk = Kdim >> 5;
  int cur = 0;
  for (int kt = 0; kt < nk; ++kt) {
    if (kt + 1 < nk) stage(cur ^ 1, kt + 1);

    bf16x8 af[4], bfv[4];
#pragma unroll
    for (int i = 0; i < 4; ++i)
      af[i]  = *(const bf16x8*)&As[cur][(wm * 64 + i * 16 + fr) * 32 + se];
#pragma unroll
    for (int j = 0; j < 4; ++j)
      bfv[j] = *(const bf16x8*)&Bs[cur][(wn * 64 + j * 16 + fr) * 32 + se];

    __builtin_amdgcn_s_setprio(1);
#pragma unroll
    for (int i = 0; i < 4; ++i)
#pragma unroll
      for (int j = 0; j < 4; ++j)
        acc[i][j] = __builtin_amdgcn_mfma_f32_16x16x32_bf16(bfv[j], af[i], acc[i][j], 0, 0, 0);
    __builtin_amdgcn_s_setprio(0);

    __syncthreads();
    cur ^= 1;
  }

#pragma unroll
  for (int i = 0; i < 4; ++i) {
    const int row_g = bm * 128 + wm * 64 + i * 16 + fr;
#pragma unroll
    for (int j = 0; j < 4; ++j) {
      const int col = bn * 128 + wn * 64 + j * 16 + fg * 4;
      const float4 bv4 = *(const float4*)&bias[col];
      const float v0 = acc[i][j][0] + bv4.x;
      const float v1 = acc[i][j][1] + bv4.y;
      const float v2 = acc[i][j][2] + bv4.z;
      const float v3 = acc[i][j][3] + bv4.w;
      if (TRV && sub == 2) {
        const int b_ = row_g >> 9, s_ = row_g & 511;
        const int h_ = col >> 6, d0 = col & 63;
        ushort* vp = (ushort*)C2 + (((size_t)(b_ * HH + h_) * DHD + d0) * SS + s_);
        vp[0] = f2bf(v0); vp[SS] = f2bf(v1); vp[2 * SS] = f2bf(v2); vp[3 * SS] = f2bf(v3);
      } else if (EPI == 2) {
        ushort4 o4;
        o4.x = f2bf(gelu_t(v0)); o4.y = f2bf(gelu_t(v1));
        o4.z = f2bf(gelu_t(v2)); o4.w = f2bf(gelu_t(v3));
        *(ushort4*)&((ushort*)C0)[(size_t)row_g * Ndim + col] = o4;
      } else {
        void* Cout = sub == 0 ? C0 : (sub == 1 ? C1 : C2);
        ushort4 o4;
        o4.x = f2bf(v0); o4.y = f2bf(v1); o4.z = f2bf(v2); o4.w = f2bf(v3);
        *(ushort4*)&((ushort*)Cout)[(size_t)row_g * Ndim + col] = o4;
      }
    }
  }
}

// ================= split-K=2 GEMM for N=768 (O-proj, Wd) — bf16 partials =================
__global__ __launch_bounds__(256, 4)
void gemm_sk(const ushort* __restrict__ A, const ushort* __restrict__ Bw,
             const float* __restrict__ bias, ushort* __restrict__ P0,
             ushort* __restrict__ P1, int Kdim)
{
  __shared__ ushort As[2][128 * 32];
  __shared__ ushort Bs[2][128 * 32];

  const int id = blockIdx.y * gridDim.x + blockIdx.x;
  const int x = id & 7;
  const int r = id >> 3;
  const int bm = x * 8 + (r & 7);
  const int rest = r >> 3;           // 0..11
  const int bn = rest >> 1;
  const int sk = rest & 1;

  const int Kh = Kdim >> 1;

  const int tid = threadIdx.x;
  const int l = tid & 63, w = tid >> 6;
  const int wm = w >> 1, wn = w & 1;
  const int fr = l & 15, fg = l >> 4;

  const int srow_in = l >> 2;
  const int gks = ((l & 3) ^ ((l >> 3) & 3)) * 8;
  const ushort* Agl0 = A  + (size_t)(bm * 128 + w * 16 + srow_in) * Kdim + sk * Kh + gks;
  const ushort* Agl1 = Agl0 + (size_t)64 * Kdim;
  const ushort* Bgl0 = Bw + (size_t)(bn * 128 + w * 16 + srow_in) * Kdim + sk * Kh + gks;
  const ushort* Bgl1 = Bgl0 + (size_t)64 * Kdim;

  auto stage = [&](int b, int kt) {
    const int ko = kt * 32;
    ushort* al = &As[b][w * 64 * 8];
    ushort* bl = &Bs[b][w * 64 * 8];
    glds16(Agl0 + ko, al);
    glds16(Agl1 + ko, al + 256 * 8);
    glds16(Bgl0 + ko, bl);
    glds16(Bgl1 + ko, bl + 256 * 8);
  };

  const int se = (fg ^ ((fr >> 1) & 3)) * 8;

  f32x4 acc[4][4];
#pragma unroll
  for (int i = 0; i < 4; ++i)
#pragma unroll
    for (int j = 0; j < 4; ++j) acc[i][j] = f32x4{0.f, 0.f, 0.f, 0.f};

  stage(0, 0);
  __syncthreads();

  const int nk = Kh >> 5;
  int cur = 0;
  for (int kt = 0; kt < nk; ++kt) {
    if (kt + 1 < nk) stage(cur ^ 1, kt + 1);

    bf16x8 af[4], bfv[4];
#pragma unroll
    for (int i = 0; i < 4; ++i)
      af[i]  = *(const bf16x8*)&As[cur][(wm * 64 + i * 16 + fr) * 32 + se];
#pragma unroll
    for (int j = 0; j < 4; ++j)
      bfv[j] = *(const bf16x8*)&Bs[cur][(wn * 64 + j * 16 + fr) * 32 + se];

    __builtin_amdgcn_s_setprio(1);
#pragma unroll
    for (int i = 0; i < 4; ++i)
#pragma unroll
      for (int j = 0; j < 4; ++j)
        acc[i][j] = __builtin_amdgcn_mfma_f32_16x16x32_bf16(bfv[j], af[i], acc[i][j], 0, 0, 0);
    __builtin_amdgcn_s_setprio(0);

    __syncthreads();
    cur ^= 1;
  }

  ushort* P = sk ? P1 : P0;
  const float bs = sk ? 0.f : 1.f;
#pragma unroll
  for (int i = 0; i < 4; ++i) {
    const int row_g = bm * 128 + wm * 64 + i * 16 + fr;
#pragma unroll
    for (int j = 0; j < 4; ++j) {
      const int col = bn * 128 + wn * 64 + j * 16 + fg * 4;
      const float4 bv4 = *(const float4*)&bias[col];
      ushort4 o4;
      o4.x = f2bf(acc[i][j][0] + bv4.x * bs);
      o4.y = f2bf(acc[i][j][1] + bv4.y * bs);
      o4.z = f2bf(acc[i][j][2] + bv4.z * bs);
      o4.w = f2bf(acc[i][j][3] + bv4.w * bs);
      *(ushort4*)&P[(size_t)row_g * DD + col] = o4;
    }
  }
}

// ================= fused flash attention (V pre-transposed, QBLK=128) =================
// 512 threads = 8 waves, each wave owns 16 q-rows. grid (S/128, B*H).
// LDS layout = the GEMM's verified 0-conflict pattern: [row][32]-granule sub-arrays
// with XOR slot swizzle (slot ^ ((row>>1)&3)) applied on BOTH write and read.
// K: 2x[128][32], V: 4x[64][32], P: 4x[128][32]. 70KB total -> 2 blocks/CU.
// T14 async-STAGE: next tile's global loads issue right after staging barriers.
__global__ __launch_bounds__(512, 2)
void attn_kernel(const ushort* __restrict__ qb, const ushort* __restrict__ kb,
                 const ushort* __restrict__ vt, const float* __restrict__ relt,
                 const float* __restrict__ amask, ushort* __restrict__ ctxb)
{
  __shared__ ushort Kl[2][128 * 32];
  __shared__ ushort Vl[4][64 * 32];
  __shared__ ushort Plq[4][128 * 32];
  __shared__ float am_lds[512];
  __shared__ float rel_lds[1024];

  const int tid = threadIdx.x, lane = tid & 63, w = tid >> 6;

  int lin = blockIdx.y * gridDim.x + blockIdx.x;        // 0..767
  lin = (lin & 7) * 96 + (lin >> 3);
  const int qt = lin & 3;
  const int bh = lin >> 2;
  const int b = bh / HH, h = bh - b * HH;
  const int fr = lane & 15, fg = lane >> 4;

  am_lds[tid] = (1.0f - amask[b * SS + tid]) * -10000.0f;
  {
    int d0 = tid - 512;
    d0 = max(-128, d0);
    rel_lds[tid] = relt[(d0 + 128) * HH + h];
    int d1 = tid;
    d1 = min(128, d1);
    rel_lds[tid + 512] = relt[(d1 + 128) * HH + h];
  }

  bf16x8 qf[2];
  {
    const int qrow = qt * 128 + w * 16 + fr;
    const ushort* p = qb + ((size_t)(b * SS + qrow) * DD) + h * DHD + fg * 8;
    qf[0] = *(const bf16x8*)p;
    qf[1] = *(const bf16x8*)(p + 32);
  }

  f32x4 o[4];
  float mrow[4], lrow[4];
#pragma unroll
  for (int r = 0; r < 4; ++r) { mrow[r] = -1e30f; lrow[r] = 0.f; }
#pragma unroll
  for (int d = 0; d < 4; ++d) o[d] = f32x4{0.f, 0.f, 0.f, 0.f};

  // K staging coords: row skr, 64-ushort row split into half (kalf) x 4 slots of 8
  const int skr  = tid >> 2;                 // 0..127
  const int kalf = (tid & 3) >> 1;           // which [128][32] half
  const int ks0  = 2 * (tid & 1);            // base slot within half
  const int kmw  = (skr >> 1) & 3;           // write swizzle mask
  // V staging coords: row vrow, 128-ushort row split into 4 quarters x 4 slots
  const int vrow = tid >> 3;                 // 0..63
  const int vq   = (tid & 7) >> 1;           // quarter
  const int vs0  = 2 * (tid & 1);
  const int vmw  = (vrow >> 1) & 3;
  const ushort* vgl = vt + ((size_t)bh * DHD + vrow) * SS + (tid & 7) * 16;

  // read-side swizzled slot offset (lane-constant): (fg ^ ((fr>>1)&3))*8
  const int sse = (fg ^ ((fr >> 1) & 3)) * 8;

  const int qg0 = qt * 128 + w * 16;

  int4 kr0, kr1, vr0, vr1;
  auto load_tile = [&](int kt) {
    const size_t gbase = ((size_t)(b * SS + kt * 128 + skr) * DD) + h * DHD + (tid & 3) * 16;
    kr0 = *(const int4*)(kb + gbase);
    kr1 = *(const int4*)(kb + gbase + 8);
    const ushort* vp = vgl + kt * 128;
    vr0 = *(const int4*)(vp);
    vr1 = *(const int4*)(vp + 8);
  };

  load_tile(0);

  for (int kt = 0; kt < 4; ++kt) {
    __syncthreads();   // previous tile's LDS reads complete
    *(int4*)&Kl[kalf][skr * 32 + ((ks0 ^ kmw) * 8)]       = kr0;
    *(int4*)&Kl[kalf][skr * 32 + (((ks0 + 1) ^ kmw) * 8)] = kr1;
    *(int4*)&Vl[vq][vrow * 32 + ((vs0 ^ vmw) * 8)]        = vr0;
    *(int4*)&Vl[vq][vrow * 32 + (((vs0 + 1) ^ vmw) * 8)]  = vr1;
    __syncthreads();   // staging visible

    // issue next tile's loads early — latency hides under this tile's compute
    if (kt + 1 < 4) load_tile(kt + 1);

    float sv[8][4];
    __builtin_amdgcn_s_setprio(1);
#pragma unroll
    for (int kc = 0; kc < 8; ++kc) {
      f32x4 s = f32x4{0.f, 0.f, 0.f, 0.f};
      const int kr = kc * 16 + fr;
      bf16x8 kf0 = *(const bf16x8*)&Kl[0][kr * 32 + sse];
      bf16x8 kf1 = *(const bf16x8*)&Kl[1][kr * 32 + sse];
      s = __builtin_amdgcn_mfma_f32_16x16x32_bf16(qf[0], kf0, s, 0, 0, 0);
      s = __builtin_amdgcn_mfma_f32_16x16x32_bf16(qf[1], kf1, s, 0, 0, 0);
      const int col = kt * 128 + kc * 16 + fr;
      const float am = am_lds[col];
      const int ridx = col - qg0 - fg * 4 + 512;
#pragma unroll
      for (int r = 0; r < 4; ++r)
        sv[kc][r] = s[r] * 0.125f + rel_lds[ridx - r] + am;
    }
    __builtin_amdgcn_s_setprio(0);

    float ef[4];
#pragma unroll
    for (int r = 0; r < 4; ++r) {
      float tmax = sv[0][r];
#pragma unroll
      for (int kc = 1; kc < 8; ++kc) tmax = fmaxf(tmax, sv[kc][r]);
#pragma unroll
      for (int off = 1; off < 16; off <<= 1) tmax = fmaxf(tmax, __shfl_xor(tmax, off));
      const float mnew = fmaxf(mrow[r], tmax);
      ef[r] = __expf(mrow[r] - mnew);
      float psum = 0.f;
      const int prow = w * 16 + fg * 4 + r;
      const int mp = (prow >> 1) & 3;
#pragma unroll
      for (int kc = 0; kc < 8; ++kc) {
        float p = __expf(sv[kc][r] - mnew);
        psum += p;
        const int slot_ = 2 * (kc & 1) + (fr >> 3);
        Plq[kc >> 1][prow * 32 + ((slot_ ^ mp) * 8) + (fr & 7)] = f2bf(p);
      }
#pragma unroll
      for (int off = 1; off < 16; off <<= 1) psum += __shfl_xor(psum, off);
      lrow[r] = lrow[r] * ef[r] + psum;
      mrow[r] = mnew;
    }
#pragma unroll
    for (int dc = 0; dc < 4; ++dc)
#pragma unroll
      for (int r = 0; r < 4; ++r) o[dc][r] *= ef[r];
    __syncthreads();

    __builtin_amdgcn_s_setprio(1);
#pragma unroll
    for (int dc = 0; dc < 4; ++dc) {
      const int vr_ = dc * 16 + fr;
      const int pr_ = w * 16 + fr;
#pragma unroll
      for (int ks = 0; ks < 4; ++ks) {
        bf16x8 pf = *(const bf16x8*)&Plq[ks][pr_ * 32 + sse];
        bf16x8 vf = *(const bf16x8*)&Vl[ks][vr_ * 32 + sse];
        o[dc] = __builtin_amdgcn_mfma_f32_16x16x32_bf16(pf, vf, o[dc], 0, 0, 0);
      }
    }
    __builtin_amdgcn_s_setprio(0);
  }

#pragma unroll
  for (int dc = 0; dc < 4; ++dc)
#pragma unroll
    for (int r = 0; r < 4; ++r) {
      const int qg = qt * 128 + w * 16 + fg * 4 + r;
      const float v = o[dc][r] / lrow[r];
      ctxb[((size_t)(b * SS + qg) * DD) + h * DHD + dc * 16 + fr] = f2bf(v);
    }
}

// ================= host launch =================
extern "C" void kernel_launch(void* const* d_in, const int* in_sizes, int n_in,
                              void* d_out, int out_size, void* d_ws, size_t ws_size,
                              hipStream_t stream) {
  const int*   ids   = (const int*)d_in[0];
  const float* amask = (const float*)d_in[1];
  const float* wemb  = (const float*)d_in[2];
  const float* pemb  = (const float*)d_in[3];
  const float* eln_w = (const float*)d_in[4];
  const float* eln_b = (const float*)d_in[5];
  const float* relt  = (const float*)d_in[6];
  const float* Wq    = (const float*)d_in[7];
  const float* bq    = (const float*)d_in[8];
  const float* Wk    = (const float*)d_in[9];
  const float* bk    = (const float*)d_in[10];
  const float* Wv    = (const float*)d_in[11];
  const float* bv    = (const float*)d_in[12];
  const float* Wo    = (const float*)d_in[13];
  const float* bo    = (const float*)d_in[14];
  const float* aln_w = (const float*)d_in[15];
  const float* aln_b = (const float*)d_in[16];
  const float* Wi    = (const float*)d_in[17];
  const float* bi    = (const float*)d_in[18];
  const float* Wd    = (const float*)d_in[19];
  const float* bd    = (const float*)d_in[20];
  const float* oln_w = (const float*)d_in[21];
  const float* oln_b = (const float*)d_in[22];

  size_t off = 0;
  auto carve = [&](size_t bytes) -> void* {
    void* r = (char*)d_ws + off;
    off += (bytes + 255) & ~(size_t)255;
    return r;
  };
  float*  hf     = (float*) carve((size_t)MM * DD * 4);
  ushort* hb     = (ushort*)carve((size_t)MM * DD * 2);
  ushort* qbuf   = (ushort*)carve((size_t)MM * DD * 2);
  ushort* kbuf   = (ushort*)carve((size_t)MM * DD * 2);
  ushort* vbuf   = (ushort*)carve((size_t)MM * DD * 2);   // vT[b][h][d][s]
  ushort* ctxb   = (ushort*)carve((size_t)MM * DD * 2);
  ushort* gout   = (ushort*)carve((size_t)MM * DD * 2);   // split-K partial 0 (bf16)
  ushort* gout2  = (ushort*)carve((size_t)MM * DD * 2);   // split-K partial 1 (bf16)
  ushort* interb = (ushort*)carve((size_t)MM * FF * 2);
  const int PD = DD * DD;
  const int PF = FF * DD;
  ushort* wBded  = (ushort*)carve((size_t)2 * PF * 2);    // Wi,Wd bf16 (dedicated)

  ushort* wA = interb;   // Wq,Wk,Wv,Wo bf16 in interb's dead window

  embed_ln_kernel<<<MM, 256, 0, stream>>>(ids, wemb, pemb, eln_w, eln_b, hf, hb);

  const dim3 gQKV(MM / 128, 3 * (DD / 128));  // 64 x 18
  const dim3 gSK(MM / 128, 2 * (DD / 128));   // 64 x 12 (split-K=2)
  const dim3 gF(MM / 128, FF / 128);          // 64 x 24
  const dim3 gA(SS / 128, BB * HH);           // 4 x 192
  const dim3 gC(PF / 1024, 6);                // 2304 x 6

  for (int l = 0; l < LL; ++l) {
    const size_t wo  = (size_t)l * PD;
    const size_t wio = (size_t)l * PF;

    convw6<<<gC, 256, 0, stream>>>(Wq + wo, Wk + wo, Wv + wo, Wo + wo,
                                   Wi + wio, Wd + wio, wA, wBded, PD, PF);

    gemm_ker<0, true><<<gQKV, 256, 0, stream>>>(hb, wA, wA + PD, wA + 2 * PD,
                                                bq + l * DD, bk + l * DD, bv + l * DD,
                                                qbuf, kbuf, vbuf, DD, DD / 128);

    attn_kernel<<<gA, 512, 0, stream>>>(qbuf, kbuf, vbuf, relt, amask, ctxb);

    gemm_sk<<<gSK, 256, 0, stream>>>(ctxb, wA + 3 * PD, bo + l * DD, gout, gout2, DD);
    add_ln2_kernel<<<MM, 256, 0, stream>>>(hf, gout, gout2,
                                           aln_w + l * DD, aln_b + l * DD, hf, hb);

    gemm_ker<2, false><<<gF, 256, 0, stream>>>(hb, wBded, wBded, wBded,
                                               bi + l * FF, bi + l * FF, bi + l * FF,
                                               interb, interb, interb, DD, FF / 128);
    gemm_sk<<<gSK, 256, 0, stream>>>(interb, wBded + PF, bd + l * DD, gout, gout2, FF);

    float* outp = (l == LL - 1) ? (float*)d_out : hf;
    add_ln2_kernel<<<MM, 256, 0, stream>>>(hf, gout, gout2,
                                           oln_w + l * DD, oln_b + l * DD, outp, hb);
  }
}

// Round 17
// 2924.157 us; speedup vs baseline: 2.6290x; 1.0224x over previous
//
#include <hip/hip_runtime.h>
#include <hip/hip_bf16.h>
#include <cstdint>
#include <cstddef>

// ---------------- config ----------------
#define BB 16
#define SS 512
#define DD 768
#define HH 12
#define FF 3072
#define LL 12
#define DHD 64
#define MM (BB*SS)   // 8192 rows
#define LOG2E 1.4426950408889634f

typedef __attribute__((ext_vector_type(8))) short bf16x8;
typedef __attribute__((ext_vector_type(4))) float f32x4;

// hardware RNE conversion — compiler lowers pairs to v_cvt_pk_bf16_f32
__device__ __forceinline__ ushort f2bf(float f) {
  return __bfloat16_as_ushort(__float2bfloat16(f));
}
__device__ __forceinline__ float bf2f(ushort u) {
  union { uint32_t u; float f; } x; x.u = (uint32_t)u << 16;
  return x.f;
}

__device__ __forceinline__ void glds16(const ushort* g, ushort* l) {
  __builtin_amdgcn_global_load_lds((__attribute__((address_space(1))) void*)g,
                                   (__attribute__((address_space(3))) void*)l,
                                   16, 0, 0);
}

__device__ __forceinline__ float gelu_t(float v) {
  // v * sigmoid(2y), y = 0.79788456(v + 0.044715 v^3); == tanh-gelu
  const float v2 = v * v;
  const float u = v * (-1.5957691216f - 0.0713548163f * v2);   // -2y
  return v / (1.f + __expf(u));
}

// ================= weight f32 -> bf16 conversion (6 tensors, one dispatch) ==========
__global__ __launch_bounds__(256)
void convw6(const float* __restrict__ s0, const float* __restrict__ s1,
            const float* __restrict__ s2, const float* __restrict__ s3,
            const float* __restrict__ s4, const float* __restrict__ s5,
            ushort* __restrict__ dA, ushort* __restrict__ dB, int perD, int perF)
{
  const int y = blockIdx.y;
  const int per = (y < 4) ? perD : perF;
  const int i = (blockIdx.x * 256 + threadIdx.x) * 4;
  if (i >= per) return;
  const float* s = y == 0 ? s0 : y == 1 ? s1 : y == 2 ? s2 : y == 3 ? s3 : y == 4 ? s4 : s5;
  ushort* dst = (y < 4) ? (dA + (size_t)y * perD) : (dB + (size_t)(y - 4) * perF);
  const float4 v = *(const float4*)(s + i);
  ushort4 o;
  o.x = f2bf(v.x); o.y = f2bf(v.y); o.z = f2bf(v.z); o.w = f2bf(v.w);
  *(ushort4*)(dst + i) = o;
}

// ================= embedding + LayerNorm -> bf16 residual/activation =================
__global__ __launch_bounds__(256)
void embed_ln_kernel(const int* __restrict__ ids, const float* __restrict__ wemb,
                     const float* __restrict__ pemb, const float* __restrict__ g,
                     const float* __restrict__ bt, ushort* __restrict__ hb)
{
  const int row = blockIdx.x;
  const int s = row & (SS - 1);
  const int id = ids[row];
  const float* wp = wemb + (size_t)id * DD;
  const float* pp = pemb + (size_t)s * DD;
  const int tid = threadIdx.x;
  float v[3]; float sum = 0.f, sq = 0.f;
#pragma unroll
  for (int j = 0; j < 3; ++j) {
    int e = tid + j * 256;
    v[j] = wp[e] + pp[e];
    sum += v[j]; sq += v[j] * v[j];
  }
  __shared__ float red[2][4];
#pragma unroll
  for (int off = 32; off >= 1; off >>= 1) { sum += __shfl_xor(sum, off); sq += __shfl_xor(sq, off); }
  const int lane = tid & 63, wid = tid >> 6;
  if (lane == 0) { red[0][wid] = sum; red[1][wid] = sq; }
  __syncthreads();
  sum = red[0][0] + red[0][1] + red[0][2] + red[0][3];
  sq  = red[1][0] + red[1][1] + red[1][2] + red[1][3];
  const float mean = sum * (1.f / DD);
  const float var  = sq  * (1.f / DD) - mean * mean;
  const float rstd = rsqrtf(var + 1e-12f);
  const size_t base = (size_t)row * DD;
#pragma unroll
  for (int j = 0; j < 3; ++j) {
    int e = tid + j * 256;
    float o = (v[j] - mean) * rstd * g[e] + bt[e];
    hb[base + e] = f2bf(o);
  }
}

// ========== residual(bf16) + two bf16 split-K partials + LayerNorm -> bf16 ==========
// The residual stream IS the previous LN output (hb) — no separate f32 copy needed.
// FOUT: additionally write f32 output (final layer -> d_out).
template<bool FOUT>
__global__ __launch_bounds__(256)
void add_ln2_kernel(const ushort* __restrict__ res, const ushort* __restrict__ p0,
                    const ushort* __restrict__ p1, const float* __restrict__ g,
                    const float* __restrict__ bt, ushort* __restrict__ hb,
                    float* __restrict__ fout)
{
  const int row = blockIdx.x;
  const int tid = threadIdx.x;
  const size_t base = (size_t)row * DD;
  float v[3]; float sum = 0.f, sq = 0.f;
#pragma unroll
  for (int j = 0; j < 3; ++j) {
    int e = tid + j * 256;
    v[j] = bf2f(res[base + e]) + bf2f(p0[base + e]) + bf2f(p1[base + e]);
    sum += v[j]; sq += v[j] * v[j];
  }
  __shared__ float red[2][4];
#pragma unroll
  for (int off = 32; off >= 1; off >>= 1) { sum += __shfl_xor(sum, off); sq += __shfl_xor(sq, off); }
  const int lane = tid & 63, wid = tid >> 6;
  if (lane == 0) { red[0][wid] = sum; red[1][wid] = sq; }
  __syncthreads();
  sum = red[0][0] + red[0][1] + red[0][2] + red[0][3];
  sq  = red[1][0] + red[1][1] + red[1][2] + red[1][3];
  const float mean = sum * (1.f / DD);
  const float var  = sq  * (1.f / DD) - mean * mean;
  const float rstd = rsqrtf(var + 1e-12f);
#pragma unroll
  for (int j = 0; j < 3; ++j) {
    int e = tid + j * 256;
    float o = (v[j] - mean) * rstd * g[e] + bt[e];
    hb[base + e] = f2bf(o);
    if (FOUT) fout[base + e] = o;
  }
}

// ================= GEMM: C[M,N] = A[M,K](bf16) @ Bw[N,K](bf16)^T + bias =================
// m97 schedule: 128x128 tile, BK=32, double-buffered (32KB -> 4 blocks/CU),
// XOR-swizzled staging (0 bank conflicts), swapped-operand MFMA, vectorized epilogue.
// L2-locality mapping: XCD x owns bm-slab [x*8, x*8+8) across ALL bn (FETCH 115->30MB).
// NOTE: do NOT raise the occupancy bound past 4 — at 5 the allocator drops below
// 64 VGPR, spills acc to scratch, and WRITE_SIZE explodes 49->713MB (round 13).
// EPI 0: bf16 out; 2: bf16 out + gelu. TRV: sub==2 writes vT[b][h][d][s].
template<int EPI, bool TRV>
__global__ __launch_bounds__(256, 4)
void gemm_ker(const ushort* __restrict__ A,
              const ushort* __restrict__ B0, const ushort* __restrict__ B1,
              const ushort* __restrict__ B2,
              const float* __restrict__ bias0, const float* __restrict__ bias1,
              const float* __restrict__ bias2,
              void* __restrict__ C0, void* __restrict__ C1, void* __restrict__ C2,
              int Kdim, int nblk)
{
  __shared__ ushort As[2][128 * 32];
  __shared__ ushort Bs[2][128 * 32];

  const int id = blockIdx.y * gridDim.x + blockIdx.x;
  const int x = id & 7;
  const int r = id >> 3;
  const int bm = x * 8 + (r & 7);
  const int bnAll = r >> 3;
  const int sub = bnAll / nblk;
  const int bn = bnAll - sub * nblk;

  const ushort* Bw  = sub == 0 ? B0 : (sub == 1 ? B1 : B2);
  const float* bias = sub == 0 ? bias0 : (sub == 1 ? bias1 : bias2);
  const int Ndim = nblk * 128;

  const int tid = threadIdx.x;
  const int l = tid & 63, w = tid >> 6;
  const int wm = w >> 1, wn = w & 1;
  const int fr = l & 15, fg = l >> 4;

  const int srow_in = l >> 2;
  const int gks = ((l & 3) ^ ((l >> 3) & 3)) * 8;
  const ushort* Agl0 = A  + (size_t)(bm * 128 + w * 16 + srow_in) * Kdim + gks;
  const ushort* Agl1 = Agl0 + (size_t)64 * Kdim;
  const ushort* Bgl0 = Bw + (size_t)(bn * 128 + w * 16 + srow_in) * Kdim + gks;
  const ushort* Bgl1 = Bgl0 + (size_t)64 * Kdim;

  auto stage = [&](int b, int kt) {
    const int ko = kt * 32;
    ushort* al = &As[b][w * 64 * 8];
    ushort* bl = &Bs[b][w * 64 * 8];
    glds16(Agl0 + ko, al);
    glds16(Agl1 + ko, al + 256 * 8);
    glds16(Bgl0 + ko, bl);
    glds16(Bgl1 + ko, bl + 256 * 8);
  };

  const int se = (fg ^ ((fr >> 1) & 3)) * 8;

  f32x4 acc[4][4];
#pragma unroll
  for (int i = 0; i < 4; ++i)
#pragma unroll
    for (int j = 0; j < 4; ++j) acc[i][j] = f32x4{0.f, 0.f, 0.f, 0.f};

  stage(0, 0);
  __syncthreads();

  const int nk = Kdim >> 5;
  int cur = 0;
  for (int kt = 0; kt < nk; ++kt) {
    if (kt + 1 < nk) stage(cur ^ 1, kt + 1);

    bf16x8 af[4], bfv[4];
#pragma unroll
    for (int i = 0; i < 4; ++i)
      af[i]  = *(const bf16x8*)&As[cur][(wm * 64 + i * 16 + fr) * 32 + se];
#pragma unroll
    for (int j = 0; j < 4; ++j)
      bfv[j] = *(const bf16x8*)&Bs[cur][(wn * 64 + j * 16 + fr) * 32 + se];

    __builtin_amdgcn_s_setprio(1);
#pragma unroll
    for (int i = 0; i < 4; ++i)
#pragma unroll
      for (int j = 0; j < 4; ++j)
        acc[i][j] = __builtin_amdgcn_mfma_f32_16x16x32_bf16(bfv[j], af[i], acc[i][j], 0, 0, 0);
    __builtin_amdgcn_s_setprio(0);

    __syncthreads();
    cur ^= 1;
  }

#pragma unroll
  for (int i = 0; i < 4; ++i) {
    const int row_g = bm * 128 + wm * 64 + i * 16 + fr;
#pragma unroll
    for (int j = 0; j < 4; ++j) {
      const int col = bn * 128 + wn * 64 + j * 16 + fg * 4;
      const float4 bv4 = *(const float4*)&bias[col];
      const float v0 = acc[i][j][0] + bv4.x;
      const float v1 = acc[i][j][1] + bv4.y;
      const float v2 = acc[i][j][2] + bv4.z;
      const float v3 = acc[i][j][3] + bv4.w;
      if (TRV && sub == 2) {
        const int b_ = row_g >> 9, s_ = row_g & 511;
        const int h_ = col >> 6, d0 = col & 63;
        ushort* vp = (ushort*)C2 + (((size_t)(b_ * HH + h_) * DHD + d0) * SS + s_);
        vp[0] = f2bf(v0); vp[SS] = f2bf(v1); vp[2 * SS] = f2bf(v2); vp[3 * SS] = f2bf(v3);
      } else if (EPI == 2) {
        ushort4 o4;
        o4.x = f2bf(gelu_t(v0)); o4.y = f2bf(gelu_t(v1));
        o4.z = f2bf(gelu_t(v2)); o4.w = f2bf(gelu_t(v3));
        *(ushort4*)&((ushort*)C0)[(size_t)row_g * Ndim + col] = o4;
      } else {
        void* Cout = sub == 0 ? C0 : (sub == 1 ? C1 : C2);
        ushort4 o4;
        o4.x = f2bf(v0); o4.y = f2bf(v1); o4.z = f2bf(v2); o4.w = f2bf(v3);
        *(ushort4*)&((ushort*)Cout)[(size_t)row_g * Ndim + col] = o4;
      }
    }
  }
}

// ================= split-K=2 GEMM for N=768 (O-proj, Wd) — bf16 partials =================
__global__ __launch_bounds__(256, 4)
void gemm_sk(const ushort* __restrict__ A, const ushort* __restrict__ Bw,
             const float* __restrict__ bias, ushort* __restrict__ P0,
             ushort* __restrict__ P1, int Kdim)
{
  __shared__ ushort As[2][128 * 32];
  __shared__ ushort Bs[2][128 * 32];

  const int id = blockIdx.y * gridDim.x + blockIdx.x;
  const int x = id & 7;
  const int r = id >> 3;
  const int bm = x * 8 + (r & 7);
  const int rest = r >> 3;           // 0..11
  const int bn = rest >> 1;
  const int sk = rest & 1;

  const int Kh = Kdim >> 1;

  const int tid = threadIdx.x;
  const int l = tid & 63, w = tid >> 6;
  const int wm = w >> 1, wn = w & 1;
  const int fr = l & 15, fg = l >> 4;

  const int srow_in = l >> 2;
  const int gks = ((l & 3) ^ ((l >> 3) & 3)) * 8;
  const ushort* Agl0 = A  + (size_t)(bm * 128 + w * 16 + srow_in) * Kdim + sk * Kh + gks;
  const ushort* Agl1 = Agl0 + (size_t)64 * Kdim;
  const ushort* Bgl0 = Bw + (size_t)(bn * 128 + w * 16 + srow_in) * Kdim + sk * Kh + gks;
  const ushort* Bgl1 = Bgl0 + (size_t)64 * Kdim;

  auto stage = [&](int b, int kt) {
    const int ko = kt * 32;
    ushort* al = &As[b][w * 64 * 8];
    ushort* bl = &Bs[b][w * 64 * 8];
    glds16(Agl0 + ko, al);
    glds16(Agl1 + ko, al + 256 * 8);
    glds16(Bgl0 + ko, bl);
    glds16(Bgl1 + ko, bl + 256 * 8);
  };

  const int se = (fg ^ ((fr >> 1) & 3)) * 8;

  f32x4 acc[4][4];
#pragma unroll
  for (int i = 0; i < 4; ++i)
#pragma unroll
    for (int j = 0; j < 4; ++j) acc[i][j] = f32x4{0.f, 0.f, 0.f, 0.f};

  stage(0, 0);
  __syncthreads();

  const int nk = Kh >> 5;
  int cur = 0;
  for (int kt = 0; kt < nk; ++kt) {
    if (kt + 1 < nk) stage(cur ^ 1, kt + 1);

    bf16x8 af[4], bfv[4];
#pragma unroll
    for (int i = 0; i < 4; ++i)
      af[i]  = *(const bf16x8*)&As[cur][(wm * 64 + i * 16 + fr) * 32 + se];
#pragma unroll
    for (int j = 0; j < 4; ++j)
      bfv[j] = *(const bf16x8*)&Bs[cur][(wn * 64 + j * 16 + fr) * 32 + se];

    __builtin_amdgcn_s_setprio(1);
#pragma unroll
    for (int i = 0; i < 4; ++i)
#pragma unroll
      for (int j = 0; j < 4; ++j)
        acc[i][j] = __builtin_amdgcn_mfma_f32_16x16x32_bf16(bfv[j], af[i], acc[i][j], 0, 0, 0);
    __builtin_amdgcn_s_setprio(0);

    __syncthreads();
    cur ^= 1;
  }

  ushort* P = sk ? P1 : P0;
  const float bs = sk ? 0.f : 1.f;
#pragma unroll
  for (int i = 0; i < 4; ++i) {
    const int row_g = bm * 128 + wm * 64 + i * 16 + fr;
#pragma unroll
    for (int j = 0; j < 4; ++j) {
      const int col = bn * 128 + wn * 64 + j * 16 + fg * 4;
      const float4 bv4 = *(const float4*)&bias[col];
      ushort4 o4;
      o4.x = f2bf(acc[i][j][0] + bv4.x * bs);
      o4.y = f2bf(acc[i][j][1] + bv4.y * bs);
      o4.z = f2bf(acc[i][j][2] + bv4.z * bs);
      o4.w = f2bf(acc[i][j][3] + bv4.w * bs);
      *(ushort4*)&P[(size_t)row_g * DD + col] = o4;
    }
  }
}

// ================= fused flash attention (V pre-transposed, QBLK=128) =================
// 512 threads = 8 waves, each wave owns 16 q-rows. grid (S/128, B*H).
// LDS layout = the GEMM's verified 0-conflict pattern with both-sides XOR swizzle.
// exp2-domain softmax: log2e folded into the score scale and rel/mask tables so the
// inner exp is a bare v_exp (no per-element mul).
// T14 async-STAGE: next tile's global loads issue right after staging barriers.
__global__ __launch_bounds__(512, 2)
void attn_kernel(const ushort* __restrict__ qb, const ushort* __restrict__ kb,
                 const ushort* __restrict__ vt, const float* __restrict__ relt,
                 const float* __restrict__ amask, ushort* __restrict__ ctxb)
{
  __shared__ ushort Kl[2][128 * 32];
  __shared__ ushort Vl[4][64 * 32];
  __shared__ ushort Plq[4][128 * 32];
  __shared__ float am_lds[512];
  __shared__ float rel_lds[1024];

  const int tid = threadIdx.x, lane = tid & 63, w = tid >> 6;

  int lin = blockIdx.y * gridDim.x + blockIdx.x;        // 0..767
  lin = (lin & 7) * 96 + (lin >> 3);
  const int qt = lin & 3;
  const int bh = lin >> 2;
  const int b = bh / HH, h = bh - b * HH;
  const int fr = lane & 15, fg = lane >> 4;

  am_lds[tid] = (1.0f - amask[b * SS + tid]) * (-10000.0f * LOG2E);
  {
    int d0 = tid - 512;
    d0 = max(-128, d0);
    rel_lds[tid] = relt[(d0 + 128) * HH + h] * LOG2E;
    int d1 = tid;
    d1 = min(128, d1);
    rel_lds[tid + 512] = relt[(d1 + 128) * HH + h] * LOG2E;
  }

  bf16x8 qf[2];
  {
    const int qrow = qt * 128 + w * 16 + fr;
    const ushort* p = qb + ((size_t)(b * SS + qrow) * DD) + h * DHD + fg * 8;
    qf[0] = *(const bf16x8*)p;
    qf[1] = *(const bf16x8*)(p + 32);
  }

  f32x4 o[4];
  float mrow[4], lrow[4];
#pragma unroll
  for (int r = 0; r < 4; ++r) { mrow[r] = -1e30f; lrow[r] = 0.f; }
#pragma unroll
  for (int d = 0; d < 4; ++d) o[d] = f32x4{0.f, 0.f, 0.f, 0.f};

  const int skr  = tid >> 2;                 // K row 0..127
  const int kalf = (tid & 3) >> 1;           // which [128][32] half
  const int ks0  = 2 * (tid & 1);
  const int kmw  = (skr >> 1) & 3;
  const int vrow = tid >> 3;                 // V row (d) 0..63
  const int vq   = (tid & 7) >> 1;
  const int vs0  = 2 * (tid & 1);
  const int vmw  = (vrow >> 1) & 3;
  const ushort* vgl = vt + ((size_t)bh * DHD + vrow) * SS + (tid & 7) * 16;

  const int sse = (fg ^ ((fr >> 1) & 3)) * 8;

  const int qg0 = qt * 128 + w * 16;

  int4 kr0, kr1, vr0, vr1;
  auto load_tile = [&](int kt) {
    const size_t gbase = ((size_t)(b * SS + kt * 128 + skr) * DD) + h * DHD + (tid & 3) * 16;
    kr0 = *(const int4*)(kb + gbase);
    kr1 = *(const int4*)(kb + gbase + 8);
    const ushort* vp = vgl + kt * 128;
    vr0 = *(const int4*)(vp);
    vr1 = *(const int4*)(vp + 8);
  };

  load_tile(0);

  for (int kt = 0; kt < 4; ++kt) {
    __syncthreads();
    *(int4*)&Kl[kalf][skr * 32 + ((ks0 ^ kmw) * 8)]       = kr0;
    *(int4*)&Kl[kalf][skr * 32 + (((ks0 + 1) ^ kmw) * 8)] = kr1;
    *(int4*)&Vl[vq][vrow * 32 + ((vs0 ^ vmw) * 8)]        = vr0;
    *(int4*)&Vl[vq][vrow * 32 + (((vs0 + 1) ^ vmw) * 8)]  = vr1;
    __syncthreads();

    if (kt + 1 < 4) load_tile(kt + 1);

    float sv[8][4];
    __builtin_amdgcn_s_setprio(1);
#pragma unroll
    for (int kc = 0; kc < 8; ++kc) {
      f32x4 s = f32x4{0.f, 0.f, 0.f, 0.f};
      const int kr = kc * 16 + fr;
      bf16x8 kf0 = *(const bf16x8*)&Kl[0][kr * 32 + sse];
      bf16x8 kf1 = *(const bf16x8*)&Kl[1][kr * 32 + sse];
      s = __builtin_amdgcn_mfma_f32_16x16x32_bf16(qf[0], kf0, s, 0, 0, 0);
      s = __builtin_amdgcn_mfma_f32_16x16x32_bf16(qf[1], kf1, s, 0, 0, 0);
      const int col = kt * 128 + kc * 16 + fr;
      const float am = am_lds[col];
      const int ridx = col - qg0 - fg * 4 + 512;
#pragma unroll
      for (int r = 0; r < 4; ++r)
        sv[kc][r] = s[r] * (0.125f * LOG2E) + rel_lds[ridx - r] + am;
    }
    __builtin_amdgcn_s_setprio(0);

    float ef[4];
#pragma unroll
    for (int r = 0; r < 4; ++r) {
      float tmax = sv[0][r];
#pragma unroll
      for (int kc = 1; kc < 8; ++kc) tmax = fmaxf(tmax, sv[kc][r]);
#pragma unroll
      for (int off = 1; off < 16; off <<= 1) tmax = fmaxf(tmax, __shfl_xor(tmax, off));
      const float mnew = fmaxf(mrow[r], tmax);
      ef[r] = exp2f(mrow[r] - mnew);
      float psum = 0.f;
      const int prow = w * 16 + fg * 4 + r;
      const int mp = (prow >> 1) & 3;
#pragma unroll
      for (int kc = 0; kc < 8; ++kc) {
        float p = exp2f(sv[kc][r] - mnew);
        psum += p;
        const int slot_ = 2 * (kc & 1) + (fr >> 3);
        Plq[kc >> 1][prow * 32 + ((slot_ ^ mp) * 8) + (fr & 7)] = f2bf(p);
      }
#pragma unroll
      for (int off = 1; off < 16; off <<= 1) psum += __shfl_xor(psum, off);
      lrow[r] = lrow[r] * ef[r] + psum;
      mrow[r] = mnew;
    }
#pragma unroll
    for (int dc = 0; dc < 4; ++dc)
#pragma unroll
      for (int r = 0; r < 4; ++r) o[dc][r] *= ef[r];
    __syncthreads();

    __builtin_amdgcn_s_setprio(1);
#pragma unroll
    for (int dc = 0; dc < 4; ++dc) {
      const int vr_ = dc * 16 + fr;
      const int pr_ = w * 16 + fr;
#pragma unroll
      for (int ks = 0; ks < 4; ++ks) {
        bf16x8 pf = *(const bf16x8*)&Plq[ks][pr_ * 32 + sse];
        bf16x8 vf = *(const bf16x8*)&Vl[ks][vr_ * 32 + sse];
        o[dc] = __builtin_amdgcn_mfma_f32_16x16x32_bf16(pf, vf, o[dc], 0, 0, 0);
      }
    }
    __builtin_amdgcn_s_setprio(0);
  }

#pragma unroll
  for (int dc = 0; dc < 4; ++dc)
#pragma unroll
    for (int r = 0; r < 4; ++r) {
      const int qg = qt * 128 + w * 16 + fg * 4 + r;
      const float v = o[dc][r] / lrow[r];
      ctxb[((size_t)(b * SS + qg) * DD) + h * DHD + dc * 16 + fr] = f2bf(v);
    }
}

// ================= host launch =================
extern "C" void kernel_launch(void* const* d_in, const int* in_sizes, int n_in,
                              void* d_out, int out_size, void* d_ws, size_t ws_size,
                              hipStream_t stream) {
  const int*   ids   = (const int*)d_in[0];
  const float* amask = (const float*)d_in[1];
  const float* wemb  = (const float*)d_in[2];
  const float* pemb  = (const float*)d_in[3];
  const float* eln_w = (const float*)d_in[4];
  const float* eln_b = (const float*)d_in[5];
  const float* relt  = (const float*)d_in[6];
  const float* Wq    = (const float*)d_in[7];
  const float* bq    = (const float*)d_in[8];
  const float* Wk    = (const float*)d_in[9];
  const float* bk    = (const float*)d_in[10];
  const float* Wv    = (const float*)d_in[11];
  const float* bv    = (const float*)d_in[12];
  const float* Wo    = (const float*)d_in[13];
  const float* bo    = (const float*)d_in[14];
  const float* aln_w = (const float*)d_in[15];
  const float* aln_b = (const float*)d_in[16];
  const float* Wi    = (const float*)d_in[17];
  const float* bi    = (const float*)d_in[18];
  const float* Wd    = (const float*)d_in[19];
  const float* bd    = (const float*)d_in[20];
  const float* oln_w = (const float*)d_in[21];
  const float* oln_b = (const float*)d_in[22];

  size_t off = 0;
  auto carve = [&](size_t bytes) -> void* {
    void* r = (char*)d_ws + off;
    off += (bytes + 255) & ~(size_t)255;
    return r;
  };
  ushort* hb     = (ushort*)carve((size_t)MM * DD * 2);   // bf16 residual/activation
  ushort* qbuf   = (ushort*)carve((size_t)MM * DD * 2);
  ushort* kbuf   = (ushort*)carve((size_t)MM * DD * 2);
  ushort* vbuf   = (ushort*)carve((size_t)MM * DD * 2);   // vT[b][h][d][s]
  ushort* ctxb   = (ushort*)carve((size_t)MM * DD * 2);
  ushort* gout   = (ushort*)carve((size_t)MM * DD * 2);   // split-K partial 0 (bf16)
  ushort* gout2  = (ushort*)carve((size_t)MM * DD * 2);   // split-K partial 1 (bf16)
  ushort* interb = (ushort*)carve((size_t)MM * FF * 2);
  const int PD = DD * DD;
  const int PF = FF * DD;
  ushort* wBded  = (ushort*)carve((size_t)2 * PF * 2);    // Wi,Wd bf16 (dedicated)

  ushort* wA = interb;   // Wq,Wk,Wv,Wo bf16 in interb's dead window

  embed_ln_kernel<<<MM, 256, 0, stream>>>(ids, wemb, pemb, eln_w, eln_b, hb);

  const dim3 gQKV(MM / 128, 3 * (DD / 128));  // 64 x 18
  const dim3 gSK(MM / 128, 2 * (DD / 128));   // 64 x 12 (split-K=2)
  const dim3 gF(MM / 128, FF / 128);          // 64 x 24
  const dim3 gA(SS / 128, BB * HH);           // 4 x 192
  const dim3 gC(PF / 1024, 6);                // 2304 x 6

  for (int l = 0; l < LL; ++l) {
    const size_t wo  = (size_t)l * PD;
    const size_t wio = (size_t)l * PF;

    convw6<<<gC, 256, 0, stream>>>(Wq + wo, Wk + wo, Wv + wo, Wo + wo,
                                   Wi + wio, Wd + wio, wA, wBded, PD, PF);

    gemm_ker<0, true><<<gQKV, 256, 0, stream>>>(hb, wA, wA + PD, wA + 2 * PD,
                                                bq + l * DD, bk + l * DD, bv + l * DD,
                                                qbuf, kbuf, vbuf, DD, DD / 128);

    attn_kernel<<<gA, 512, 0, stream>>>(qbuf, kbuf, vbuf, relt, amask, ctxb);

    gemm_sk<<<gSK, 256, 0, stream>>>(ctxb, wA + 3 * PD, bo + l * DD, gout, gout2, DD);
    add_ln2_kernel<false><<<MM, 256, 0, stream>>>(hb, gout, gout2,
                                                  aln_w + l * DD, aln_b + l * DD,
                                                  hb, nullptr);

    gemm_ker<2, false><<<gF, 256, 0, stream>>>(hb, wBded, wBded, wBded,
                                               bi + l * FF, bi + l * FF, bi + l * FF,
                                               interb, interb, interb, DD, FF / 128);
    gemm_sk<<<gSK, 256, 0, stream>>>(interb, wBded + PF, bd + l * DD, gout, gout2, FF);

    if (l == LL - 1)
      add_ln2_kernel<true><<<MM, 256, 0, stream>>>(hb, gout, gout2,
                                                   oln_w + l * DD, oln_b + l * DD,
                                                   hb, (float*)d_out);
    else
      add_ln2_kernel<false><<<MM, 256, 0, stream>>>(hb, gout, gout2,
                                                    oln_w + l * DD, oln_b + l * DD,
                                                    hb, nullptr);
  }
}